// Round 3
// baseline (538.491 us; speedup 1.0000x reference)
//
#include <hip/hip_runtime.h>

typedef unsigned short u16;
typedef unsigned int u32;
typedef float f32x4 __attribute__((ext_vector_type(4)));
typedef short s16x8 __attribute__((ext_vector_type(8)));

struct alignas(8) U16x4 { u16 a, b, c, d; };

#define DEV static __device__ __forceinline__

DEV u16 f2bf(float f) {
  u32 x = __float_as_uint(f);
  x += 0x7fffu + ((x >> 16) & 1u);
  return (u16)(x >> 16);
}
DEV float bf2f(u16 u) { return __uint_as_float(((u32)u) << 16); }
DEV f32x4 fz4() { f32x4 z = {0.f, 0.f, 0.f, 0.f}; return z; }

// Problem constants: B=2, S=64, L=256, H=8, C=64, D=512, 3D=1536, M=B*S*L=32768

// ---------------------------------------------------------------------------
// fp32 -> bf16 convert (vectorized), n4 = elements/4
__global__ __launch_bounds__(256) void k_cvt(const float* __restrict__ in,
                                             u16* __restrict__ outp, int n4) {
  int i = blockIdx.x * 256 + threadIdx.x;
  if (i < n4) {
    f32x4 v = reinterpret_cast<const f32x4*>(in)[i];
    U16x4 r = {f2bf(v.x), f2bf(v.y), f2bf(v.z), f2bf(v.w)};
    reinterpret_cast<U16x4*>(outp)[i] = r;
  }
}

// ---------------------------------------------------------------------------
// C[M,1536] = A[M,512] (bf16) * W[1536,512]^T (bf16) + bias, C bf16.
// 128x128 tile, BK=32, 4 waves (2x2), each wave 64x64 = 4x4 MFMA frags.
__global__ __launch_bounds__(256) void k_gemm_qkv(
    const u16* __restrict__ A, const u16* __restrict__ W,
    const float* __restrict__ bias, u16* __restrict__ Co) {
  __shared__ u16 As[128][40];
  __shared__ u16 Ws[128][40];
  const int bx = blockIdx.x, by = blockIdx.y;
  const int t = threadIdx.x;
  const int w = t >> 6, l = t & 63;
  const int wr = w >> 1, wc = w & 1;
  const int lr = l & 15, lk = l >> 4;

  f32x4 acc[4][4];
#pragma unroll
  for (int i = 0; i < 4; i++)
#pragma unroll
    for (int j = 0; j < 4; j++) acc[i][j] = fz4();

  const int sr = t >> 1;          // staging row 0..127
  const int sc = (t & 1) * 16;    // staging col half
  const u16* Ap = A + (size_t)(by * 128 + sr) * 512 + sc;
  const u16* Wp = W + (size_t)(bx * 128 + sr) * 512 + sc;

  for (int kt = 0; kt < 16; ++kt) {
    const int k0 = kt * 32;
    __syncthreads();
#pragma unroll
    for (int u = 0; u < 4; u++) {
      *reinterpret_cast<U16x4*>(&As[sr][sc + u * 4]) =
          *reinterpret_cast<const U16x4*>(Ap + k0 + u * 4);
      *reinterpret_cast<U16x4*>(&Ws[sr][sc + u * 4]) =
          *reinterpret_cast<const U16x4*>(Wp + k0 + u * 4);
    }
    __syncthreads();
    s16x8 aq[4], bq[4];
#pragma unroll
    for (int mi = 0; mi < 4; mi++)
      aq[mi] = *reinterpret_cast<const s16x8*>(&As[wr * 64 + mi * 16 + lr][lk * 8]);
#pragma unroll
    for (int ni = 0; ni < 4; ni++)
      bq[ni] = *reinterpret_cast<const s16x8*>(&Ws[wc * 64 + ni * 16 + lr][lk * 8]);
#pragma unroll
    for (int mi = 0; mi < 4; mi++)
#pragma unroll
      for (int ni = 0; ni < 4; ni++)
        acc[mi][ni] = __builtin_amdgcn_mfma_f32_16x16x32_bf16(aq[mi], bq[ni], acc[mi][ni], 0, 0, 0);
  }

#pragma unroll
  for (int ni = 0; ni < 4; ni++) {
    const int col = bx * 128 + wc * 64 + ni * 16 + lr;
    const float bv = bias[col];
#pragma unroll
    for (int mi = 0; mi < 4; mi++) {
      const int row0 = by * 128 + wr * 64 + mi * 16 + lk * 4;
#pragma unroll
      for (int q = 0; q < 4; q++)
        Co[(size_t)(row0 + q) * 1536 + col] = f2bf(acc[mi][ni][q] + bv);
    }
  }
}

// ---------------------------------------------------------------------------
// FUSED row attention: per (b,s,h, qtile of 32): QK^T (32x256) -> softmax ->
// PV (32x64). P lives in LDS only. 4 waves: scores split keys 64/wave,
// PV splits output cols 16/wave.
__global__ __launch_bounds__(256) void k_row_attn(
    const u16* __restrict__ qkv, u16* __restrict__ O) {
  __shared__ u16 Qs[32][72];       //  4608 B
  __shared__ u16 KV[256 * 72];     // 36864 B: Ks[256][72], later Vt[64][264]
  __shared__ u16 Plds[32][264];    // 16896 B
  __shared__ float red[2][4][32];  //  1024 B
  const int qt = blockIdx.x;       // 0..7  (32-query tile)
  const int bsh = blockIdx.y;      // (b*S+s)*H + h
  const int h = bsh & 7, bs = bsh >> 3;
  const u16* base = qkv + (size_t)bs * 256 * 1536 + h * 64;
  const int t = threadIdx.x;
  const int r8 = t >> 3, c0 = (t & 7) * 8;

  // ---- stage Q (32 rows x 64 cols) and K (256 rows x 64 cols) ----
  {
    const size_t qrow = (size_t)(qt * 32 + r8) * 1536;
    *reinterpret_cast<U16x4*>(&Qs[r8][c0]) =
        *reinterpret_cast<const U16x4*>(&base[qrow + c0]);
    *reinterpret_cast<U16x4*>(&Qs[r8][c0 + 4]) =
        *reinterpret_cast<const U16x4*>(&base[qrow + c0 + 4]);
#pragma unroll
    for (int v = 0; v < 8; v++) {
      const int kr = r8 + v * 32;
      const size_t krow = (size_t)kr * 1536 + 512;
      *reinterpret_cast<U16x4*>(&KV[kr * 72 + c0]) =
          *reinterpret_cast<const U16x4*>(&base[krow + c0]);
      *reinterpret_cast<U16x4*>(&KV[kr * 72 + c0 + 4]) =
          *reinterpret_cast<const U16x4*>(&base[krow + c0 + 4]);
    }
  }
  __syncthreads();

  const int w = t >> 6, lane = t & 63, lr = lane & 15, lk = lane >> 4;

  // ---- scores: wave w handles keys [w*64, w*64+64) ----
  f32x4 sc[2][4];
#pragma unroll
  for (int i = 0; i < 2; i++)
#pragma unroll
    for (int j = 0; j < 4; j++) sc[i][j] = fz4();
#pragma unroll
  for (int ks = 0; ks < 2; ks++) {
    s16x8 aq[2], bq[4];
#pragma unroll
    for (int mi = 0; mi < 2; mi++)
      aq[mi] = *reinterpret_cast<const s16x8*>(&Qs[mi * 16 + lr][ks * 32 + lk * 8]);
#pragma unroll
    for (int ni = 0; ni < 4; ni++)
      bq[ni] = *reinterpret_cast<const s16x8*>(&KV[(w * 64 + ni * 16 + lr) * 72 + ks * 32 + lk * 8]);
#pragma unroll
    for (int mi = 0; mi < 2; mi++)
#pragma unroll
      for (int ni = 0; ni < 4; ni++)
        sc[mi][ni] = __builtin_amdgcn_mfma_f32_16x16x32_bf16(aq[mi], bq[ni], sc[mi][ni], 0, 0, 0);
  }

  // ---- softmax across full 256 keys (4 waves) ----
  float mx[2][4];
#pragma unroll
  for (int mi = 0; mi < 2; mi++)
#pragma unroll
    for (int q = 0; q < 4; q++)
      mx[mi][q] = fmaxf(fmaxf(sc[mi][0][q], sc[mi][1][q]),
                        fmaxf(sc[mi][2][q], sc[mi][3][q]));
#pragma unroll
  for (int d = 1; d < 16; d <<= 1)
#pragma unroll
    for (int mi = 0; mi < 2; mi++)
#pragma unroll
      for (int q = 0; q < 4; q++)
        mx[mi][q] = fmaxf(mx[mi][q], __shfl_xor(mx[mi][q], d));
  if (lr == 0)
#pragma unroll
    for (int mi = 0; mi < 2; mi++)
#pragma unroll
      for (int q = 0; q < 4; q++) red[0][w][mi * 16 + lk * 4 + q] = mx[mi][q];
  __syncthreads();
  float mg[2][4], sm[2][4];
#pragma unroll
  for (int mi = 0; mi < 2; mi++)
#pragma unroll
    for (int q = 0; q < 4; q++) {
      const int r0 = mi * 16 + lk * 4 + q;
      mg[mi][q] = fmaxf(fmaxf(red[0][0][r0], red[0][1][r0]),
                        fmaxf(red[0][2][r0], red[0][3][r0]));
      sm[mi][q] = 0.f;
    }
#pragma unroll
  for (int mi = 0; mi < 2; mi++)
#pragma unroll
    for (int ni = 0; ni < 4; ni++)
#pragma unroll
      for (int q = 0; q < 4; q++) {
        float p = __expf(sc[mi][ni][q] - mg[mi][q]);
        sc[mi][ni][q] = p;
        sm[mi][q] += p;
      }
#pragma unroll
  for (int d = 1; d < 16; d <<= 1)
#pragma unroll
    for (int mi = 0; mi < 2; mi++)
#pragma unroll
      for (int q = 0; q < 4; q++) sm[mi][q] += __shfl_xor(sm[mi][q], d);
  if (lr == 0)
#pragma unroll
    for (int mi = 0; mi < 2; mi++)
#pragma unroll
      for (int q = 0; q < 4; q++) red[1][w][mi * 16 + lk * 4 + q] = sm[mi][q];
  __syncthreads();
  // write normalized P (bf16) into LDS, row-major [32][264]
#pragma unroll
  for (int mi = 0; mi < 2; mi++)
#pragma unroll
    for (int q = 0; q < 4; q++) {
      const int r0 = mi * 16 + lk * 4 + q;
      const float inv = 1.f / (red[1][0][r0] + red[1][1][r0] + red[1][2][r0] + red[1][3][r0]);
#pragma unroll
      for (int ni = 0; ni < 4; ni++)
        Plds[r0][w * 64 + ni * 16 + lr] = f2bf(sc[mi][ni][q] * inv);
    }
  __syncthreads();  // P visible; Ks no longer needed (scores done pre-barrier)

  // ---- stage V transposed into KV: Vt[c][k], pitch 264 ----
#pragma unroll
  for (int v = 0; v < 8; v++) {
    const int k = r8 + v * 32;
    const size_t vrow = (size_t)k * 1536 + 1024;
    U16x4 a = *reinterpret_cast<const U16x4*>(&base[vrow + c0]);
    U16x4 b = *reinterpret_cast<const U16x4*>(&base[vrow + c0 + 4]);
    KV[(c0 + 0) * 264 + k] = a.a; KV[(c0 + 1) * 264 + k] = a.b;
    KV[(c0 + 2) * 264 + k] = a.c; KV[(c0 + 3) * 264 + k] = a.d;
    KV[(c0 + 4) * 264 + k] = b.a; KV[(c0 + 5) * 264 + k] = b.b;
    KV[(c0 + 6) * 264 + k] = b.c; KV[(c0 + 7) * 264 + k] = b.d;
  }
  __syncthreads();

  // ---- PV: O[32 q][64 c]; wave w handles cols [w*16, w*16+16) ----
  f32x4 o[2];
  o[0] = fz4(); o[1] = fz4();
#pragma unroll
  for (int ks = 0; ks < 8; ks++) {
    s16x8 vb = *reinterpret_cast<const s16x8*>(&KV[(w * 16 + lr) * 264 + ks * 32 + lk * 8]);
#pragma unroll
    for (int mi = 0; mi < 2; mi++) {
      s16x8 pa = *reinterpret_cast<const s16x8*>(&Plds[mi * 16 + lr][ks * 32 + lk * 8]);
      o[mi] = __builtin_amdgcn_mfma_f32_16x16x32_bf16(pa, vb, o[mi], 0, 0, 0);
    }
  }
  const size_t ob = (size_t)bs * 256 * 512 + h * 64;
#pragma unroll
  for (int mi = 0; mi < 2; mi++)
#pragma unroll
    for (int q = 0; q < 4; q++) {
      const int lrow = qt * 32 + mi * 16 + lk * 4 + q;
      O[ob + (size_t)lrow * 512 + w * 16 + lr] = f2bf(o[mi][q]);
    }
}

// ---------------------------------------------------------------------------
// Fused column attention: per (b,l,h): QK^T (64x64,K=64) -> softmax -> PV.
__global__ __launch_bounds__(256) void k_col(
    const u16* __restrict__ qkv, u16* __restrict__ O) {
  __shared__ u16 Qs[64][72];
  __shared__ u16 Ks[64][72];
  __shared__ u16 Pl[64][72];
  __shared__ u16 Vt[64][72];
  __shared__ float red[2][64][2];
  const int bid = blockIdx.x;
  const int h = bid & 7, bl = bid >> 3;
  const int l_ = bl & 255, b = bl >> 8;
  const size_t base0 = ((size_t)b * 16384 + l_) * 1536 + h * 64;  // i=0 row
  const int t = threadIdx.x;
  const int r = t >> 2, c0 = (t & 3) * 16;
  const size_t rowoff = base0 + (size_t)r * 393216;  // + i*256*1536
#pragma unroll
  for (int u = 0; u < 4; u++) {
    *reinterpret_cast<U16x4*>(&Qs[r][c0 + u * 4]) =
        *reinterpret_cast<const U16x4*>(&qkv[rowoff + c0 + u * 4]);
    *reinterpret_cast<U16x4*>(&Ks[r][c0 + u * 4]) =
        *reinterpret_cast<const U16x4*>(&qkv[rowoff + 512 + c0 + u * 4]);
  }
  __syncthreads();
  const int w = t >> 6, l = t & 63, lr = l & 15, lk = l >> 4;
  const int wr = w >> 1, wc = w & 1;
  f32x4 acc[2][2];
#pragma unroll
  for (int i = 0; i < 2; i++)
#pragma unroll
    for (int j = 0; j < 2; j++) acc[i][j] = fz4();
#pragma unroll
  for (int ks = 0; ks < 2; ks++) {
    s16x8 aq[2], bq[2];
#pragma unroll
    for (int mi = 0; mi < 2; mi++)
      aq[mi] = *reinterpret_cast<const s16x8*>(&Qs[wr * 32 + mi * 16 + lr][ks * 32 + lk * 8]);
#pragma unroll
    for (int ni = 0; ni < 2; ni++)
      bq[ni] = *reinterpret_cast<const s16x8*>(&Ks[wc * 32 + ni * 16 + lr][ks * 32 + lk * 8]);
#pragma unroll
    for (int mi = 0; mi < 2; mi++)
#pragma unroll
      for (int ni = 0; ni < 2; ni++)
        acc[mi][ni] = __builtin_amdgcn_mfma_f32_16x16x32_bf16(aq[mi], bq[ni], acc[mi][ni], 0, 0, 0);
  }
  // softmax over keys j (cols, split across wc)
  float mloc[2][4];
#pragma unroll
  for (int mi = 0; mi < 2; mi++)
#pragma unroll
    for (int q = 0; q < 4; q++) mloc[mi][q] = fmaxf(acc[mi][0][q], acc[mi][1][q]);
#pragma unroll
  for (int d = 1; d < 16; d <<= 1)
#pragma unroll
    for (int mi = 0; mi < 2; mi++)
#pragma unroll
      for (int q = 0; q < 4; q++)
        mloc[mi][q] = fmaxf(mloc[mi][q], __shfl_xor(mloc[mi][q], d));
  if (lr == 0)
#pragma unroll
    for (int mi = 0; mi < 2; mi++)
#pragma unroll
      for (int q = 0; q < 4; q++) red[0][wr * 32 + mi * 16 + lk * 4 + q][wc] = mloc[mi][q];
  __syncthreads();
  float mg[2][4], ss[2][4];
#pragma unroll
  for (int mi = 0; mi < 2; mi++)
#pragma unroll
    for (int q = 0; q < 4; q++) {
      const int r0 = wr * 32 + mi * 16 + lk * 4 + q;
      mg[mi][q] = fmaxf(red[0][r0][0], red[0][r0][1]);
      ss[mi][q] = 0.f;
    }
#pragma unroll
  for (int mi = 0; mi < 2; mi++)
#pragma unroll
    for (int ni = 0; ni < 2; ni++)
#pragma unroll
      for (int q = 0; q < 4; q++) {
        float p = __expf(acc[mi][ni][q] - mg[mi][q]);
        acc[mi][ni][q] = p;
        ss[mi][q] += p;
      }
#pragma unroll
  for (int d = 1; d < 16; d <<= 1)
#pragma unroll
    for (int mi = 0; mi < 2; mi++)
#pragma unroll
      for (int q = 0; q < 4; q++) ss[mi][q] += __shfl_xor(ss[mi][q], d);
  if (lr == 0)
#pragma unroll
    for (int mi = 0; mi < 2; mi++)
#pragma unroll
      for (int q = 0; q < 4; q++) red[1][wr * 32 + mi * 16 + lk * 4 + q][wc] = ss[mi][q];
  __syncthreads();
#pragma unroll
  for (int mi = 0; mi < 2; mi++)
#pragma unroll
    for (int q = 0; q < 4; q++) {
      const int r0 = wr * 32 + mi * 16 + lk * 4 + q;
      const float inv = 1.f / (red[1][r0][0] + red[1][r0][1]);
#pragma unroll
      for (int ni = 0; ni < 2; ni++)
        Pl[r0][wc * 32 + ni * 16 + lr] = f2bf(acc[mi][ni][q] * inv);
    }
  __syncthreads();
  // stage V transposed: Vt[c][j]
#pragma unroll
  for (int u = 0; u < 4; u++) {
    U16x4 vv = *reinterpret_cast<const U16x4*>(&qkv[rowoff + 1024 + c0 + u * 4]);
    Vt[c0 + u * 4 + 0][r] = vv.a; Vt[c0 + u * 4 + 1][r] = vv.b;
    Vt[c0 + u * 4 + 2][r] = vv.c; Vt[c0 + u * 4 + 3][r] = vv.d;
  }
  __syncthreads();
  f32x4 acc2[2][2];
#pragma unroll
  for (int i = 0; i < 2; i++)
#pragma unroll
    for (int j = 0; j < 2; j++) acc2[i][j] = fz4();
#pragma unroll
  for (int ks = 0; ks < 2; ks++) {
    s16x8 ap[2], bp[2];
#pragma unroll
    for (int mi = 0; mi < 2; mi++)
      ap[mi] = *reinterpret_cast<const s16x8*>(&Pl[wr * 32 + mi * 16 + lr][ks * 32 + lk * 8]);
#pragma unroll
    for (int ni = 0; ni < 2; ni++)
      bp[ni] = *reinterpret_cast<const s16x8*>(&Vt[wc * 32 + ni * 16 + lr][ks * 32 + lk * 8]);
#pragma unroll
    for (int mi = 0; mi < 2; mi++)
#pragma unroll
      for (int ni = 0; ni < 2; ni++)
        acc2[mi][ni] = __builtin_amdgcn_mfma_f32_16x16x32_bf16(ap[mi], bp[ni], acc2[mi][ni], 0, 0, 0);
  }
  const size_t ob = ((size_t)b * 16384 + l_) * 512 + h * 64;
#pragma unroll
  for (int mi = 0; mi < 2; mi++)
#pragma unroll
    for (int ni = 0; ni < 2; ni++)
#pragma unroll
      for (int q = 0; q < 4; q++) {
        const int i = wr * 32 + mi * 16 + lk * 4 + q;
        const int cc = wc * 32 + ni * 16 + lr;
        O[ob + (size_t)i * 131072 + cc] = f2bf(acc2[mi][ni][q]);
      }
}

// ---------------------------------------------------------------------------
// LN variant 1: base f32 + add bf16 -> out bf16. One wave per row of 512.
__global__ __launch_bounds__(256) void k_ln1(
    const float* __restrict__ xin, const u16* __restrict__ add,
    const float* __restrict__ g, const float* __restrict__ be,
    u16* __restrict__ outp) {
  const int w = threadIdx.x >> 6, l = threadIdx.x & 63;
  const size_t row = (size_t)blockIdx.x * 4 + w;
  const size_t o = row * 512 + l * 8;
  f32x4 x0 = *reinterpret_cast<const f32x4*>(xin + o);
  f32x4 x1 = *reinterpret_cast<const f32x4*>(xin + o + 4);
  U16x4 a0 = *reinterpret_cast<const U16x4*>(add + o);
  U16x4 a1 = *reinterpret_cast<const U16x4*>(add + o + 4);
  float v[8] = {x0.x + bf2f(a0.a), x0.y + bf2f(a0.b), x0.z + bf2f(a0.c), x0.w + bf2f(a0.d),
                x1.x + bf2f(a1.a), x1.y + bf2f(a1.b), x1.z + bf2f(a1.c), x1.w + bf2f(a1.d)};
  float s = 0.f, sq = 0.f;
#pragma unroll
  for (int i = 0; i < 8; i++) { s += v[i]; sq += v[i] * v[i]; }
#pragma unroll
  for (int d = 1; d < 64; d <<= 1) { s += __shfl_xor(s, d); sq += __shfl_xor(sq, d); }
  const float mu = s * (1.f / 512.f);
  const float var = sq * (1.f / 512.f) - mu * mu;
  const float rstd = rsqrtf(fmaxf(var, 0.f) + 1e-5f);
  U16x4 r0, r1;
  const float* gp = g + l * 8;
  const float* bp = be + l * 8;
  r0.a = f2bf((v[0] - mu) * rstd * gp[0] + bp[0]);
  r0.b = f2bf((v[1] - mu) * rstd * gp[1] + bp[1]);
  r0.c = f2bf((v[2] - mu) * rstd * gp[2] + bp[2]);
  r0.d = f2bf((v[3] - mu) * rstd * gp[3] + bp[3]);
  r1.a = f2bf((v[4] - mu) * rstd * gp[4] + bp[4]);
  r1.b = f2bf((v[5] - mu) * rstd * gp[5] + bp[5]);
  r1.c = f2bf((v[6] - mu) * rstd * gp[6] + bp[6]);
  r1.d = f2bf((v[7] - mu) * rstd * gp[7] + bp[7]);
  *reinterpret_cast<U16x4*>(outp + o) = r0;
  *reinterpret_cast<U16x4*>(outp + o + 4) = r1;
}

// ---------------------------------------------------------------------------
// LN variant 2: base bf16 + add bf16 -> out f32.
__global__ __launch_bounds__(256) void k_ln2(
    const u16* __restrict__ xin, const u16* __restrict__ add,
    const float* __restrict__ g, const float* __restrict__ be,
    float* __restrict__ outp) {
  const int w = threadIdx.x >> 6, l = threadIdx.x & 63;
  const size_t row = (size_t)blockIdx.x * 4 + w;
  const size_t o = row * 512 + l * 8;
  U16x4 x0 = *reinterpret_cast<const U16x4*>(xin + o);
  U16x4 x1 = *reinterpret_cast<const U16x4*>(xin + o + 4);
  U16x4 a0 = *reinterpret_cast<const U16x4*>(add + o);
  U16x4 a1 = *reinterpret_cast<const U16x4*>(add + o + 4);
  float v[8] = {bf2f(x0.a) + bf2f(a0.a), bf2f(x0.b) + bf2f(a0.b),
                bf2f(x0.c) + bf2f(a0.c), bf2f(x0.d) + bf2f(a0.d),
                bf2f(x1.a) + bf2f(a1.a), bf2f(x1.b) + bf2f(a1.b),
                bf2f(x1.c) + bf2f(a1.c), bf2f(x1.d) + bf2f(a1.d)};
  float s = 0.f, sq = 0.f;
#pragma unroll
  for (int i = 0; i < 8; i++) { s += v[i]; sq += v[i] * v[i]; }
#pragma unroll
  for (int d = 1; d < 64; d <<= 1) { s += __shfl_xor(s, d); sq += __shfl_xor(sq, d); }
  const float mu = s * (1.f / 512.f);
  const float var = sq * (1.f / 512.f) - mu * mu;
  const float rstd = rsqrtf(fmaxf(var, 0.f) + 1e-5f);
  f32x4 g0 = *reinterpret_cast<const f32x4*>(g + l * 8);
  f32x4 g1v = *reinterpret_cast<const f32x4*>(g + l * 8 + 4);
  f32x4 b0 = *reinterpret_cast<const f32x4*>(be + l * 8);
  f32x4 b1 = *reinterpret_cast<const f32x4*>(be + l * 8 + 4);
  f32x4 o0, o1;
  o0.x = (v[0] - mu) * rstd * g0.x + b0.x;
  o0.y = (v[1] - mu) * rstd * g0.y + b0.y;
  o0.z = (v[2] - mu) * rstd * g0.z + b0.z;
  o0.w = (v[3] - mu) * rstd * g0.w + b0.w;
  o1.x = (v[4] - mu) * rstd * g1v.x + b1.x;
  o1.y = (v[5] - mu) * rstd * g1v.y + b1.y;
  o1.z = (v[6] - mu) * rstd * g1v.z + b1.z;
  o1.w = (v[7] - mu) * rstd * g1v.w + b1.w;
  *reinterpret_cast<f32x4*>(outp + o) = o0;
  *reinterpret_cast<f32x4*>(outp + o + 4) = o1;
}

// ---------------------------------------------------------------------------
extern "C" void kernel_launch(void* const* d_in, const int* in_sizes, int n_in,
                              void* d_out, int out_size, void* d_ws, size_t ws_size,
                              hipStream_t stream) {
  const float* x     = (const float*)d_in[0];
  const float* w_row = (const float*)d_in[1];
  const float* b_row = (const float*)d_in[2];
  const float* w_col = (const float*)d_in[3];
  const float* b_col = (const float*)d_in[4];
  const float* g1    = (const float*)d_in[5];
  const float* be1   = (const float*)d_in[6];
  const float* g2    = (const float*)d_in[7];
  const float* be2   = (const float*)d_in[8];
  float* out = (float*)d_out;
  char* ws = (char*)d_ws;

  // workspace layout (bytes) — total 202,899,456
  u16* abf   = (u16*)(ws);                  //  33,554,432  x as bf16
  u16* qkv   = (u16*)(ws + 33554432);       // 100,663,296  [32768][1536]
  u16* attnb = (u16*)(ws + 134217728);      //  33,554,432  attn out bf16
  u16* out1b = (u16*)(ws + 167772160);      //  33,554,432  LN1 out bf16
  u16* wbf   = (u16*)(ws + 201326592);      //   1,572,864  W bf16
  const size_t NEED = 202899456;
  if (ws_size < NEED) {  // graceful failure signal instead of GPU fault
    hipMemsetAsync(d_out, 0, (size_t)out_size * 4, stream);
    return;
  }

  // ---- stage 1: row attention ----
  k_cvt<<<16384, 256, 0, stream>>>(x, abf, 4194304);
  k_cvt<<<768, 256, 0, stream>>>(w_row, wbf, 196608);
  k_gemm_qkv<<<dim3(12, 256), 256, 0, stream>>>(abf, wbf, b_row, qkv);
  k_row_attn<<<dim3(8, 1024), 256, 0, stream>>>(qkv, attnb);
  k_ln1<<<8192, 256, 0, stream>>>(x, attnb, g1, be1, out1b);

  // ---- stage 2: column attention ----
  k_cvt<<<768, 256, 0, stream>>>(w_col, wbf, 196608);
  k_gemm_qkv<<<dim3(12, 256), 256, 0, stream>>>(out1b, wbf, b_col, qkv);
  k_col<<<4096, 256, 0, stream>>>(qkv, attnb);
  k_ln2<<<8192, 256, 0, stream>>>(out1b, attnb, g2, be2, out);
}

// Round 6
// 431.549 us; speedup vs baseline: 1.2478x; 1.2478x over previous
//
#include <hip/hip_runtime.h>

typedef unsigned short u16;
typedef unsigned int u32;
typedef float f32x4 __attribute__((ext_vector_type(4)));
typedef short s16x8 __attribute__((ext_vector_type(8)));

struct alignas(8) U16x4 { u16 a, b, c, d; };

#define DEV static __device__ __forceinline__

DEV u16 f2bf(float f) {
  u32 x = __float_as_uint(f);
  x += 0x7fffu + ((x >> 16) & 1u);
  return (u16)(x >> 16);
}
DEV float bf2f(u16 u) { return __uint_as_float(((u32)u) << 16); }
DEV f32x4 fz4() { f32x4 z = {0.f, 0.f, 0.f, 0.f}; return z; }

// async global->LDS, 16B per lane; lds dest must be wave-uniform base (+lane*16 by HW)
DEV void gl16(const u16* g, u16* l) {
  __builtin_amdgcn_global_load_lds(
      (const __attribute__((address_space(1))) u32*)g,
      (__attribute__((address_space(3))) u32*)l, 16, 0, 0);
}

// Problem constants: B=2, S=64, L=256, H=8, C=64, D=512, 3D=1536, M=32768

// ---------------------------------------------------------------------------
__global__ __launch_bounds__(256) void k_cvt(const float* __restrict__ in,
                                             u16* __restrict__ outp, int n4) {
  int i = blockIdx.x * 256 + threadIdx.x;
  if (i < n4) {
    f32x4 v = reinterpret_cast<const f32x4*>(in)[i];
    U16x4 r = {f2bf(v.x), f2bf(v.y), f2bf(v.z), f2bf(v.w)};
    reinterpret_cast<U16x4*>(outp)[i] = r;
  }
}

// ---------------------------------------------------------------------------
// GEMM C[M,1536] = A[M,512]*W[1536,512]^T + bias. m97-style: global_load_lds
// staging, 128x128 tile, BK=32, linear LDS [128][32] per operand.
// MODE 0 (stage 1): Q/K -> per-head [bsh][l][c]; V -> TRANSPOSED [bsh][c][l]
//   via MFMA operand swap (regs<->lane roles) keeping stores coalesced.
// MODE 1 (stage 2): Q/K -> per-(b,l,h) [blh][s][c]; V -> row-major [row][512].
template<int MODE>
__global__ __launch_bounds__(256) void k_gemm(
    const u16* __restrict__ A, const u16* __restrict__ W,
    const float* __restrict__ bias,
    u16* __restrict__ D0, u16* __restrict__ D1, u16* __restrict__ D2) {
  __shared__ u16 Sg[8192];  // A[128][32] @0, W[128][32] @4096 (linear, no pad)
  // XCD swizzle: lin -> (bx,by) so each XCD owns a contiguous by-range
  const int lin = blockIdx.x;
  const int j = lin >> 3, xcd = lin & 7;
  const int bx = j % 12;
  const int by = xcd * 32 + j / 12;
  const int t = threadIdx.x;
  const int w = t >> 6, lane = t & 63, lr = lane & 15, lk = lane >> 4;
  const int wr = w >> 1, wc = w & 1;
  const bool vblk = (bx >= 8) && (MODE == 0);

  f32x4 acc[4][4];
#pragma unroll
  for (int i = 0; i < 4; i++)
#pragma unroll
    for (int jj = 0; jj < 4; jj++) acc[i][jj] = fz4();

  const int srow = w * 32 + (lane >> 2);
  const int scol = (lane & 3) * 8;
  const u16* Ap = A + (size_t)(by * 128 + srow) * 512 + scol;
  const u16* Wp = W + (size_t)(bx * 128 + srow) * 512 + scol;
  u16* lA0 = &Sg[w * 1024];
  u16* lW0 = &Sg[4096 + w * 1024];

  for (int kt = 0; kt < 16; ++kt) {
    const int k0 = kt * 32;
    __syncthreads();
    gl16(Ap + k0, lA0);
    gl16(Ap + k0 + 16 * 512, lA0 + 512);
    gl16(Wp + k0, lW0);
    gl16(Wp + k0 + 16 * 512, lW0 + 512);
    __syncthreads();
    s16x8 aq[4], bq[4];
#pragma unroll
    for (int mi = 0; mi < 4; mi++)
      aq[mi] = *reinterpret_cast<const s16x8*>(&Sg[(wr * 64 + mi * 16 + lr) * 32 + lk * 8]);
#pragma unroll
    for (int ni = 0; ni < 4; ni++)
      bq[ni] = *reinterpret_cast<const s16x8*>(&Sg[4096 + (wc * 64 + ni * 16 + lr) * 32 + lk * 8]);
    if (!vblk) {
#pragma unroll
      for (int mi = 0; mi < 4; mi++)
#pragma unroll
        for (int ni = 0; ni < 4; ni++)
          acc[mi][ni] = __builtin_amdgcn_mfma_f32_16x16x32_bf16(aq[mi], bq[ni], acc[mi][ni], 0, 0, 0);
    } else {
      // swapped: regs dim = W-row (c), lane dim = A-row (l)
#pragma unroll
      for (int mi = 0; mi < 4; mi++)
#pragma unroll
        for (int ni = 0; ni < 4; ni++)
          acc[mi][ni] = __builtin_amdgcn_mfma_f32_16x16x32_bf16(bq[ni], aq[mi], acc[mi][ni], 0, 0, 0);
    }
  }

  const int colg = bx * 2 + wc;  // col>>6
  if (MODE == 0) {
    const int bs = by >> 1;
    if (!vblk) {
      u16* dst = (colg < 8) ? D0 : D1;  // Qh : Kh
      const int h = colg & 7;
      const size_t hb = (size_t)(bs * 8 + h) * 16384;
#pragma unroll
      for (int ni = 0; ni < 4; ni++) {
        const int c = ni * 16 + lr;
        const float bv = bias[(colg << 6) + c];
#pragma unroll
        for (int mi = 0; mi < 4; mi++) {
          const int l0 = (by & 1) * 128 + wr * 64 + mi * 16 + lk * 4;
#pragma unroll
          for (int q = 0; q < 4; q++)
            dst[hb + (size_t)(l0 + q) * 64 + c] = f2bf(acc[mi][ni][q] + bv);
        }
      }
    } else {
      const int h = colg & 7;
      const size_t hb = (size_t)(bs * 8 + h) * 16384;
#pragma unroll
      for (int ni = 0; ni < 4; ni++) {
        const int c0 = ni * 16 + lk * 4;
        const f32x4 bv4 = *reinterpret_cast<const f32x4*>(&bias[(colg << 6) + c0]);
#pragma unroll
        for (int mi = 0; mi < 4; mi++) {
          const int l = (by & 1) * 128 + wr * 64 + mi * 16 + lr;
#pragma unroll
          for (int q = 0; q < 4; q++)
            D2[hb + (size_t)(c0 + q) * 256 + l] = f2bf(acc[mi][ni][q] + bv4[q]);
        }
      }
    }
  } else {
    if (colg < 16) {
      u16* dst = (colg < 8) ? D0 : D1;  // Qc2 : Kc2  [blh][s][c]
      const int h = colg & 7;
#pragma unroll
      for (int ni = 0; ni < 4; ni++) {
        const int c = ni * 16 + lr;
        const float bv = bias[(colg << 6) + c];
#pragma unroll
        for (int mi = 0; mi < 4; mi++) {
          const int r0 = by * 128 + wr * 64 + mi * 16 + lk * 4;
#pragma unroll
          for (int q = 0; q < 4; q++) {
            const int row = r0 + q;
            const int b = row >> 14, s = (row >> 8) & 63, l = row & 255;
            dst[(((size_t)(b * 256 + l) * 8 + h) * 64 + s) * 64 + c] = f2bf(acc[mi][ni][q] + bv);
          }
        }
      }
    } else {
      // V row-major [row][512]
#pragma unroll
      for (int ni = 0; ni < 4; ni++) {
        const int c512 = (bx - 8) * 128 + wc * 64 + ni * 16 + lr;
        const float bv = bias[1024 + c512];
#pragma unroll
        for (int mi = 0; mi < 4; mi++) {
          const int r0 = by * 128 + wr * 64 + mi * 16 + lk * 4;
#pragma unroll
          for (int q = 0; q < 4; q++)
            D2[(size_t)(r0 + q) * 512 + c512] = f2bf(acc[mi][ni][q] + bv);
        }
      }
    }
  }
}

// ---------------------------------------------------------------------------
// Row attention: block = (qt, bsh), 64 queries vs 256 keys. Wave owns 16 q
// rows x all 256 k (in-register softmax, 16-lane shfl). P overlays K buffer.
__global__ __launch_bounds__(256) void k_row_attn(
    const u16* __restrict__ Qh, const u16* __restrict__ Kh,
    const u16* __restrict__ Vth, u16* __restrict__ O) {
  __shared__ u16 KP[256 * 72];   // K stage [256][72]; later P [64][264]
  __shared__ u16 Vt[64 * 264];   // V^T stage [64][264]
  // swizzle: 4 sibling qt-blocks of one bsh land on the same XCD
  const int lin = blockIdx.x;
  const int qt = (lin >> 3) & 3;
  const int bsh = (lin & 7) + (lin >> 5) * 8;
  const int h = bsh & 7, bs = bsh >> 3;
  const int t = threadIdx.x, w = t >> 6, lane = t & 63, lr = lane & 15, lk = lane >> 4;
  const u16* kg = Kh + (size_t)bsh * 16384;
  const u16* vg = Vth + (size_t)bsh * 16384;
  // stage K: thread t stages the FULL 64-channel row t (bug fix: u<8, was u<4)
#pragma unroll
  for (int u = 0; u < 8; u++)
    *reinterpret_cast<s16x8*>(&KP[t * 72 + u * 8]) =
        *reinterpret_cast<const s16x8*>(&kg[t * 64 + u * 8]);
#pragma unroll
  for (int i = 0; i < 8; i++) {
    const int id = i * 256 + t;
    const int r = id >> 5, ch = id & 31;
    *reinterpret_cast<s16x8*>(&Vt[r * 264 + ch * 8]) =
        *reinterpret_cast<const s16x8*>(&vg[r * 256 + ch * 8]);
  }
  const u16* qg = Qh + (size_t)bsh * 16384 + (size_t)(qt * 64 + w * 16 + lr) * 64 + lk * 8;
  const s16x8 aq0 = *reinterpret_cast<const s16x8*>(qg);
  const s16x8 aq1 = *reinterpret_cast<const s16x8*>(qg + 32);
  __syncthreads();

  f32x4 sc[16];
#pragma unroll
  for (int ni = 0; ni < 16; ni++) sc[ni] = fz4();
#pragma unroll
  for (int ni = 0; ni < 16; ni++) {
    const s16x8 b0 = *reinterpret_cast<const s16x8*>(&KP[(ni * 16 + lr) * 72 + lk * 8]);
    sc[ni] = __builtin_amdgcn_mfma_f32_16x16x32_bf16(aq0, b0, sc[ni], 0, 0, 0);
  }
#pragma unroll
  for (int ni = 0; ni < 16; ni++) {
    const s16x8 b1 = *reinterpret_cast<const s16x8*>(&KP[(ni * 16 + lr) * 72 + 32 + lk * 8]);
    sc[ni] = __builtin_amdgcn_mfma_f32_16x16x32_bf16(aq1, b1, sc[ni], 0, 0, 0);
  }
  // softmax: rows w*16 + lk*4 + qi, reduce over 16 frags + 16 lr lanes
  float mx[4], sm[4];
#pragma unroll
  for (int qi = 0; qi < 4; qi++) {
    float m = sc[0][qi];
#pragma unroll
    for (int ni = 1; ni < 16; ni++) m = fmaxf(m, sc[ni][qi]);
    mx[qi] = m;
  }
#pragma unroll
  for (int d = 1; d < 16; d <<= 1)
#pragma unroll
    for (int qi = 0; qi < 4; qi++) mx[qi] = fmaxf(mx[qi], __shfl_xor(mx[qi], d));
#pragma unroll
  for (int qi = 0; qi < 4; qi++) sm[qi] = 0.f;
#pragma unroll
  for (int ni = 0; ni < 16; ni++)
#pragma unroll
    for (int qi = 0; qi < 4; qi++) {
      const float p = __expf(sc[ni][qi] - mx[qi]);
      sc[ni][qi] = p;
      sm[qi] += p;
    }
#pragma unroll
  for (int d = 1; d < 16; d <<= 1)
#pragma unroll
    for (int qi = 0; qi < 4; qi++) sm[qi] += __shfl_xor(sm[qi], d);
  float inv[4];
#pragma unroll
  for (int qi = 0; qi < 4; qi++) inv[qi] = 1.f / sm[qi];
  __syncthreads();  // all waves done reading K
#pragma unroll
  for (int ni = 0; ni < 16; ni++)
#pragma unroll
    for (int qi = 0; qi < 4; qi++)
      KP[(w * 16 + lk * 4 + qi) * 264 + ni * 16 + lr] = f2bf(sc[ni][qi] * inv[qi]);
  __syncthreads();

  f32x4 o[4];
#pragma unroll
  for (int mi = 0; mi < 4; mi++) o[mi] = fz4();
#pragma unroll
  for (int ks = 0; ks < 8; ks++) {
    const s16x8 vb = *reinterpret_cast<const s16x8*>(&Vt[(w * 16 + lr) * 264 + ks * 32 + lk * 8]);
#pragma unroll
    for (int mi = 0; mi < 4; mi++) {
      const s16x8 pa = *reinterpret_cast<const s16x8*>(&KP[(mi * 16 + lr) * 264 + ks * 32 + lk * 8]);
      o[mi] = __builtin_amdgcn_mfma_f32_16x16x32_bf16(pa, vb, o[mi], 0, 0, 0);
    }
  }
  const size_t ob = (size_t)bs * 131072 + (size_t)qt * 64 * 512 + h * 64 + w * 16 + lr;
#pragma unroll
  for (int mi = 0; mi < 4; mi++)
#pragma unroll
    for (int qi = 0; qi < 4; qi++)
      O[ob + (size_t)(mi * 16 + lk * 4 + qi) * 512] = f2bf(o[mi][qi]);
}

// ---------------------------------------------------------------------------
// Column attention: per (b,l,h): QK^T (64x64,K=64) -> softmax over j -> PV.
// Q/K from per-(b,l,h) contiguous tiles; V from row-major qkv2.
__global__ __launch_bounds__(256) void k_col(
    const u16* __restrict__ Qc, const u16* __restrict__ Kc,
    const u16* __restrict__ V2, u16* __restrict__ O) {
  __shared__ u16 Qs[64][72];
  __shared__ u16 Ks[64][72];
  __shared__ u16 Pl[64][72];
  __shared__ u16 Vt[64][72];
  __shared__ float red[2][64][2];
  const int bid = blockIdx.x;
  const int h = bid & 7, bl = bid >> 3;
  const int l_ = bl & 255, b = bl >> 8;
  const size_t base = ((size_t)(b * 256 + l_) * 8 + h) * 4096;
  const int t = threadIdx.x;
  const int r = t >> 2, c0 = (t & 3) * 16;
  *reinterpret_cast<s16x8*>(&Qs[r][c0]) = *reinterpret_cast<const s16x8*>(&Qc[base + r * 64 + c0]);
  *reinterpret_cast<s16x8*>(&Qs[r][c0 + 8]) = *reinterpret_cast<const s16x8*>(&Qc[base + r * 64 + c0 + 8]);
  *reinterpret_cast<s16x8*>(&Ks[r][c0]) = *reinterpret_cast<const s16x8*>(&Kc[base + r * 64 + c0]);
  *reinterpret_cast<s16x8*>(&Ks[r][c0 + 8]) = *reinterpret_cast<const s16x8*>(&Kc[base + r * 64 + c0 + 8]);
  __syncthreads();
  const int w = t >> 6, l = t & 63, lr = l & 15, lk = l >> 4;
  const int wr = w >> 1, wc = w & 1;
  f32x4 acc[2][2];
#pragma unroll
  for (int i = 0; i < 2; i++)
#pragma unroll
    for (int jj = 0; jj < 2; jj++) acc[i][jj] = fz4();
#pragma unroll
  for (int ks = 0; ks < 2; ks++) {
    s16x8 aq[2], bq[2];
#pragma unroll
    for (int mi = 0; mi < 2; mi++)
      aq[mi] = *reinterpret_cast<const s16x8*>(&Qs[wr * 32 + mi * 16 + lr][ks * 32 + lk * 8]);
#pragma unroll
    for (int ni = 0; ni < 2; ni++)
      bq[ni] = *reinterpret_cast<const s16x8*>(&Ks[wc * 32 + ni * 16 + lr][ks * 32 + lk * 8]);
#pragma unroll
    for (int mi = 0; mi < 2; mi++)
#pragma unroll
      for (int ni = 0; ni < 2; ni++)
        acc[mi][ni] = __builtin_amdgcn_mfma_f32_16x16x32_bf16(aq[mi], bq[ni], acc[mi][ni], 0, 0, 0);
  }
  float mloc[2][4];
#pragma unroll
  for (int mi = 0; mi < 2; mi++)
#pragma unroll
    for (int q = 0; q < 4; q++) mloc[mi][q] = fmaxf(acc[mi][0][q], acc[mi][1][q]);
#pragma unroll
  for (int d = 1; d < 16; d <<= 1)
#pragma unroll
    for (int mi = 0; mi < 2; mi++)
#pragma unroll
      for (int q = 0; q < 4; q++)
        mloc[mi][q] = fmaxf(mloc[mi][q], __shfl_xor(mloc[mi][q], d));
  if (lr == 0)
#pragma unroll
    for (int mi = 0; mi < 2; mi++)
#pragma unroll
      for (int q = 0; q < 4; q++) red[0][wr * 32 + mi * 16 + lk * 4 + q][wc] = mloc[mi][q];
  __syncthreads();
  float mg[2][4], ss[2][4];
#pragma unroll
  for (int mi = 0; mi < 2; mi++)
#pragma unroll
    for (int q = 0; q < 4; q++) {
      const int r0 = wr * 32 + mi * 16 + lk * 4 + q;
      mg[mi][q] = fmaxf(red[0][r0][0], red[0][r0][1]);
      ss[mi][q] = 0.f;
    }
#pragma unroll
  for (int mi = 0; mi < 2; mi++)
#pragma unroll
    for (int ni = 0; ni < 2; ni++)
#pragma unroll
      for (int q = 0; q < 4; q++) {
        const float p = __expf(acc[mi][ni][q] - mg[mi][q]);
        acc[mi][ni][q] = p;
        ss[mi][q] += p;
      }
#pragma unroll
  for (int d = 1; d < 16; d <<= 1)
#pragma unroll
    for (int mi = 0; mi < 2; mi++)
#pragma unroll
      for (int q = 0; q < 4; q++) ss[mi][q] += __shfl_xor(ss[mi][q], d);
  if (lr == 0)
#pragma unroll
    for (int mi = 0; mi < 2; mi++)
#pragma unroll
      for (int q = 0; q < 4; q++) red[1][wr * 32 + mi * 16 + lk * 4 + q][wc] = ss[mi][q];
  __syncthreads();
#pragma unroll
  for (int mi = 0; mi < 2; mi++)
#pragma unroll
    for (int q = 0; q < 4; q++) {
      const int r0 = wr * 32 + mi * 16 + lk * 4 + q;
      const float inv = 1.f / (red[1][r0][0] + red[1][r0][1]);
#pragma unroll
      for (int ni = 0; ni < 2; ni++)
        Pl[r0][wc * 32 + ni * 16 + lr] = f2bf(acc[mi][ni][q] * inv);
    }
  __syncthreads();
  {
    const u16* vg = V2 + ((size_t)(b * 64) * 256 + l_) * 512 + h * 64;
#pragma unroll
    for (int u = 0; u < 4; u++) {
      U16x4 vv = *reinterpret_cast<const U16x4*>(&vg[(size_t)r * 131072 + c0 + u * 4]);
      Vt[c0 + u * 4 + 0][r] = vv.a; Vt[c0 + u * 4 + 1][r] = vv.b;
      Vt[c0 + u * 4 + 2][r] = vv.c; Vt[c0 + u * 4 + 3][r] = vv.d;
    }
  }
  __syncthreads();
  f32x4 acc2[2][2];
#pragma unroll
  for (int i = 0; i < 2; i++)
#pragma unroll
    for (int jj = 0; jj < 2; jj++) acc2[i][jj] = fz4();
#pragma unroll
  for (int ks = 0; ks < 2; ks++) {
    s16x8 ap[2], bp[2];
#pragma unroll
    for (int mi = 0; mi < 2; mi++)
      ap[mi] = *reinterpret_cast<const s16x8*>(&Pl[wr * 32 + mi * 16 + lr][ks * 32 + lk * 8]);
#pragma unroll
    for (int ni = 0; ni < 2; ni++)
      bp[ni] = *reinterpret_cast<const s16x8*>(&Vt[wc * 32 + ni * 16 + lr][ks * 32 + lk * 8]);
#pragma unroll
    for (int mi = 0; mi < 2; mi++)
#pragma unroll
      for (int ni = 0; ni < 2; ni++)
        acc2[mi][ni] = __builtin_amdgcn_mfma_f32_16x16x32_bf16(ap[mi], bp[ni], acc2[mi][ni], 0, 0, 0);
  }
  const size_t ob = ((size_t)b * 16384 + l_) * 512 + h * 64;
#pragma unroll
  for (int mi = 0; mi < 2; mi++)
#pragma unroll
    for (int ni = 0; ni < 2; ni++)
#pragma unroll
      for (int q = 0; q < 4; q++) {
        const int i = wr * 32 + mi * 16 + lk * 4 + q;
        const int cc = wc * 32 + ni * 16 + lr;
        O[ob + (size_t)i * 131072 + cc] = f2bf(acc2[mi][ni][q]);
      }
}

// ---------------------------------------------------------------------------
__global__ __launch_bounds__(256) void k_ln1(
    const float* __restrict__ xin, const u16* __restrict__ add,
    const float* __restrict__ g, const float* __restrict__ be,
    u16* __restrict__ outp) {
  const int w = threadIdx.x >> 6, l = threadIdx.x & 63;
  const size_t row = (size_t)blockIdx.x * 4 + w;
  const size_t o = row * 512 + l * 8;
  f32x4 x0 = *reinterpret_cast<const f32x4*>(xin + o);
  f32x4 x1 = *reinterpret_cast<const f32x4*>(xin + o + 4);
  U16x4 a0 = *reinterpret_cast<const U16x4*>(add + o);
  U16x4 a1 = *reinterpret_cast<const U16x4*>(add + o + 4);
  float v[8] = {x0.x + bf2f(a0.a), x0.y + bf2f(a0.b), x0.z + bf2f(a0.c), x0.w + bf2f(a0.d),
                x1.x + bf2f(a1.a), x1.y + bf2f(a1.b), x1.z + bf2f(a1.c), x1.w + bf2f(a1.d)};
  float s = 0.f, sq = 0.f;
#pragma unroll
  for (int i = 0; i < 8; i++) { s += v[i]; sq += v[i] * v[i]; }
#pragma unroll
  for (int d = 1; d < 64; d <<= 1) { s += __shfl_xor(s, d); sq += __shfl_xor(sq, d); }
  const float mu = s * (1.f / 512.f);
  const float var = sq * (1.f / 512.f) - mu * mu;
  const float rstd = rsqrtf(fmaxf(var, 0.f) + 1e-5f);
  U16x4 r0, r1;
  const float* gp = g + l * 8;
  const float* bp = be + l * 8;
  r0.a = f2bf((v[0] - mu) * rstd * gp[0] + bp[0]);
  r0.b = f2bf((v[1] - mu) * rstd * gp[1] + bp[1]);
  r0.c = f2bf((v[2] - mu) * rstd * gp[2] + bp[2]);
  r0.d = f2bf((v[3] - mu) * rstd * gp[3] + bp[3]);
  r1.a = f2bf((v[4] - mu) * rstd * gp[4] + bp[4]);
  r1.b = f2bf((v[5] - mu) * rstd * gp[5] + bp[5]);
  r1.c = f2bf((v[6] - mu) * rstd * gp[6] + bp[6]);
  r1.d = f2bf((v[7] - mu) * rstd * gp[7] + bp[7]);
  *reinterpret_cast<U16x4*>(outp + o) = r0;
  *reinterpret_cast<U16x4*>(outp + o + 4) = r1;
}

__global__ __launch_bounds__(256) void k_ln2(
    const u16* __restrict__ xin, const u16* __restrict__ add,
    const float* __restrict__ g, const float* __restrict__ be,
    float* __restrict__ outp) {
  const int w = threadIdx.x >> 6, l = threadIdx.x & 63;
  const size_t row = (size_t)blockIdx.x * 4 + w;
  const size_t o = row * 512 + l * 8;
  U16x4 x0 = *reinterpret_cast<const U16x4*>(xin + o);
  U16x4 x1 = *reinterpret_cast<const U16x4*>(xin + o + 4);
  U16x4 a0 = *reinterpret_cast<const U16x4*>(add + o);
  U16x4 a1 = *reinterpret_cast<const U16x4*>(add + o + 4);
  float v[8] = {bf2f(x0.a) + bf2f(a0.a), bf2f(x0.b) + bf2f(a0.b),
                bf2f(x0.c) + bf2f(a0.c), bf2f(x0.d) + bf2f(a0.d),
                bf2f(x1.a) + bf2f(a1.a), bf2f(x1.b) + bf2f(a1.b),
                bf2f(x1.c) + bf2f(a1.c), bf2f(x1.d) + bf2f(a1.d)};
  float s = 0.f, sq = 0.f;
#pragma unroll
  for (int i = 0; i < 8; i++) { s += v[i]; sq += v[i] * v[i]; }
#pragma unroll
  for (int d = 1; d < 64; d <<= 1) { s += __shfl_xor(s, d); sq += __shfl_xor(sq, d); }
  const float mu = s * (1.f / 512.f);
  const float var = sq * (1.f / 512.f) - mu * mu;
  const float rstd = rsqrtf(fmaxf(var, 0.f) + 1e-5f);
  f32x4 g0 = *reinterpret_cast<const f32x4*>(g + l * 8);
  f32x4 g1v = *reinterpret_cast<const f32x4*>(g + l * 8 + 4);
  f32x4 b0 = *reinterpret_cast<const f32x4*>(be + l * 8);
  f32x4 b1 = *reinterpret_cast<const f32x4*>(be + l * 8 + 4);
  f32x4 o0, o1;
  o0.x = (v[0] - mu) * rstd * g0.x + b0.x;
  o0.y = (v[1] - mu) * rstd * g0.y + b0.y;
  o0.z = (v[2] - mu) * rstd * g0.z + b0.z;
  o0.w = (v[3] - mu) * rstd * g0.w + b0.w;
  o1.x = (v[4] - mu) * rstd * g1v.x + b1.x;
  o1.y = (v[5] - mu) * rstd * g1v.y + b1.y;
  o1.z = (v[6] - mu) * rstd * g1v.z + b1.z;
  o1.w = (v[7] - mu) * rstd * g1v.w + b1.w;
  *reinterpret_cast<f32x4*>(outp + o) = o0;
  *reinterpret_cast<f32x4*>(outp + o + 4) = o1;
}

// ---------------------------------------------------------------------------
extern "C" void kernel_launch(void* const* d_in, const int* in_sizes, int n_in,
                              void* d_out, int out_size, void* d_ws, size_t ws_size,
                              hipStream_t stream) {
  const float* x     = (const float*)d_in[0];
  const float* w_row = (const float*)d_in[1];
  const float* b_row = (const float*)d_in[2];
  const float* w_col = (const float*)d_in[3];
  const float* b_col = (const float*)d_in[4];
  const float* g1    = (const float*)d_in[5];
  const float* be1   = (const float*)d_in[6];
  const float* g2    = (const float*)d_in[7];
  const float* be2   = (const float*)d_in[8];
  float* out = (float*)d_out;
  char* ws = (char*)d_ws;

  // workspace (bytes), total 202,899,456 (known to fit from round 2)
  u16* abf   = (u16*)(ws);                  // 33.5 MB  x bf16 / stage2: Qc2
  u16* Qh    = (u16*)(ws + 33554432);       // 33.5 MB  Qh / stage2: Kc2
  u16* Kh    = (u16*)(ws + 67108864);       // 33.5 MB  Kh / stage2: V2
  u16* Vth   = (u16*)(ws + 100663296);      // 33.5 MB  V^T per-head
  u16* attnb = (u16*)(ws + 134217728);      // 33.5 MB  attention out bf16
  u16* out1b = (u16*)(ws + 167772160);      // 33.5 MB  LN1 out bf16
  u16* wbf   = (u16*)(ws + 201326592);      //  1.5 MB  W bf16
  const size_t NEED = 202899456;
  if (ws_size < NEED) {
    hipMemsetAsync(d_out, 0, (size_t)out_size * 4, stream);
    return;
  }
  u16* Qc2 = abf;
  u16* Kc2 = Qh;
  u16* V2  = Kh;

  // ---- stage 1: row attention ----
  k_cvt<<<16384, 256, 0, stream>>>(x, abf, 4194304);
  k_cvt<<<768, 256, 0, stream>>>(w_row, wbf, 196608);
  k_gemm<0><<<3072, 256, 0, stream>>>(abf, wbf, b_row, Qh, Kh, Vth);
  k_row_attn<<<4096, 256, 0, stream>>>(Qh, Kh, Vth, attnb);
  k_ln1<<<8192, 256, 0, stream>>>(x, attnb, g1, be1, out1b);

  // ---- stage 2: column attention ----
  k_cvt<<<768, 256, 0, stream>>>(w_col, wbf, 196608);
  k_gemm<1><<<3072, 256, 0, stream>>>(out1b, wbf, b_col, Qc2, Kc2, V2);
  k_col<<<4096, 256, 0, stream>>>(Qc2, Kc2, V2, attnb);
  k_ln2<<<8192, 256, 0, stream>>>(out1b, attnb, g2, be2, out);
}

// Round 7
// 417.445 us; speedup vs baseline: 1.2900x; 1.0338x over previous
//
#include <hip/hip_runtime.h>

typedef unsigned short u16;
typedef unsigned int u32;
typedef float f32x4 __attribute__((ext_vector_type(4)));
typedef short s16x8 __attribute__((ext_vector_type(8)));

struct alignas(8) U16x4 { u16 a, b, c, d; };

#define DEV static __device__ __forceinline__

DEV u16 f2bf(float f) {
  u32 x = __float_as_uint(f);
  x += 0x7fffu + ((x >> 16) & 1u);
  return (u16)(x >> 16);
}
DEV float bf2f(u16 u) { return __uint_as_float(((u32)u) << 16); }
DEV f32x4 fz4() { f32x4 z = {0.f, 0.f, 0.f, 0.f}; return z; }

// async global->LDS, 16B per lane; lds dest must be wave-uniform base (+lane*16 by HW)
DEV void gl16(const u16* g, u16* l) {
  __builtin_amdgcn_global_load_lds(
      (const __attribute__((address_space(1))) u32*)g,
      (__attribute__((address_space(3))) u32*)l, 16, 0, 0);
}

// Problem constants: B=2, S=64, L=256, H=8, C=64, D=512, 3D=1536, M=32768

// ---------------------------------------------------------------------------
__global__ __launch_bounds__(256) void k_cvt(const float* __restrict__ in,
                                             u16* __restrict__ outp, int n4) {
  int i = blockIdx.x * 256 + threadIdx.x;
  if (i < n4) {
    f32x4 v = reinterpret_cast<const f32x4*>(in)[i];
    U16x4 r = {f2bf(v.x), f2bf(v.y), f2bf(v.z), f2bf(v.w)};
    reinterpret_cast<U16x4*>(outp)[i] = r;
  }
}

// ---------------------------------------------------------------------------
// GEMM C[M,1536] = A[M,512]*W[1536,512]^T + bias. 128x128 tile, BK=32,
// DOUBLE-BUFFERED global_load_lds staging (prefetch next tile before compute,
// one barrier per K-step) — hides load latency under ds_read+MFMA.
// MODE 0 (stage 1): Q/K -> per-head [bsh][l][c]; V -> TRANSPOSED [bsh][c][l]
//   via MFMA operand swap (regs<->lane roles) keeping stores coalesced.
// MODE 1 (stage 2): Q/K -> per-(b,l,h) [blh][s][c]; V -> row-major [row][512].
template<int MODE>
__global__ __launch_bounds__(256) void k_gemm(
    const u16* __restrict__ A, const u16* __restrict__ W,
    const float* __restrict__ bias,
    u16* __restrict__ D0, u16* __restrict__ D1, u16* __restrict__ D2) {
  __shared__ u16 Sg[16384];  // dbuf: buf b at b*8192: A[128][32] @+0, W @+4096
  // XCD swizzle: lin -> (bx,by) so each XCD owns a contiguous by-range
  const int lin = blockIdx.x;
  const int j = lin >> 3, xcd = lin & 7;
  const int bx = j % 12;
  const int by = xcd * 32 + j / 12;
  const int t = threadIdx.x;
  const int w = t >> 6, lane = t & 63, lr = lane & 15, lk = lane >> 4;
  const int wr = w >> 1, wc = w & 1;
  const bool vblk = (bx >= 8) && (MODE == 0);

  f32x4 acc[4][4];
#pragma unroll
  for (int i = 0; i < 4; i++)
#pragma unroll
    for (int jj = 0; jj < 4; jj++) acc[i][jj] = fz4();

  const int srow = w * 32 + (lane >> 2);
  const int scol = (lane & 3) * 8;
  const u16* Ap = A + (size_t)(by * 128 + srow) * 512 + scol;
  const u16* Wp = W + (size_t)(bx * 128 + srow) * 512 + scol;
  const int wb = w * 1024;  // wave-local staging base (u16)

  // prologue: stage kt=0 into buffer 0
  gl16(Ap, &Sg[wb]);
  gl16(Ap + 16 * 512, &Sg[wb + 512]);
  gl16(Wp, &Sg[4096 + wb]);
  gl16(Wp + 16 * 512, &Sg[4096 + wb + 512]);
  __syncthreads();

  for (int kt = 0; kt < 16; ++kt) {
    const int cur = (kt & 1) * 8192;
    const int nxt = 8192 - cur;
    if (kt < 15) {  // issue next tile's loads BEFORE compute (latency hiding)
      const int k1 = (kt + 1) * 32;
      gl16(Ap + k1, &Sg[nxt + wb]);
      gl16(Ap + k1 + 16 * 512, &Sg[nxt + wb + 512]);
      gl16(Wp + k1, &Sg[nxt + 4096 + wb]);
      gl16(Wp + k1 + 16 * 512, &Sg[nxt + 4096 + wb + 512]);
    }
    s16x8 aq[4], bq[4];
#pragma unroll
    for (int mi = 0; mi < 4; mi++)
      aq[mi] = *reinterpret_cast<const s16x8*>(&Sg[cur + (wr * 64 + mi * 16 + lr) * 32 + lk * 8]);
#pragma unroll
    for (int ni = 0; ni < 4; ni++)
      bq[ni] = *reinterpret_cast<const s16x8*>(&Sg[cur + 4096 + (wc * 64 + ni * 16 + lr) * 32 + lk * 8]);
    if (!vblk) {
#pragma unroll
      for (int mi = 0; mi < 4; mi++)
#pragma unroll
        for (int ni = 0; ni < 4; ni++)
          acc[mi][ni] = __builtin_amdgcn_mfma_f32_16x16x32_bf16(aq[mi], bq[ni], acc[mi][ni], 0, 0, 0);
    } else {
      // swapped: regs dim = W-row (c), lane dim = A-row (l)
#pragma unroll
      for (int mi = 0; mi < 4; mi++)
#pragma unroll
        for (int ni = 0; ni < 4; ni++)
          acc[mi][ni] = __builtin_amdgcn_mfma_f32_16x16x32_bf16(bq[ni], aq[mi], acc[mi][ni], 0, 0, 0);
    }
    __syncthreads();  // drains prefetch (vmcnt) + protects buffer swap
  }

  const int colg = bx * 2 + wc;  // col>>6
  if (MODE == 0) {
    const int bs = by >> 1;
    if (!vblk) {
      u16* dst = (colg < 8) ? D0 : D1;  // Qh : Kh
      const int h = colg & 7;
      const size_t hb = (size_t)(bs * 8 + h) * 16384;
#pragma unroll
      for (int ni = 0; ni < 4; ni++) {
        const int c = ni * 16 + lr;
        const float bv = bias[(colg << 6) + c];
#pragma unroll
        for (int mi = 0; mi < 4; mi++) {
          const int l0 = (by & 1) * 128 + wr * 64 + mi * 16 + lk * 4;
#pragma unroll
          for (int q = 0; q < 4; q++)
            dst[hb + (size_t)(l0 + q) * 64 + c] = f2bf(acc[mi][ni][q] + bv);
        }
      }
    } else {
      const int h = colg & 7;
      const size_t hb = (size_t)(bs * 8 + h) * 16384;
#pragma unroll
      for (int ni = 0; ni < 4; ni++) {
        const int c0 = ni * 16 + lk * 4;
        const f32x4 bv4 = *reinterpret_cast<const f32x4*>(&bias[(colg << 6) + c0]);
#pragma unroll
        for (int mi = 0; mi < 4; mi++) {
          const int l = (by & 1) * 128 + wr * 64 + mi * 16 + lr;
#pragma unroll
          for (int q = 0; q < 4; q++)
            D2[hb + (size_t)(c0 + q) * 256 + l] = f2bf(acc[mi][ni][q] + bv4[q]);
        }
      }
    }
  } else {
    if (colg < 16) {
      u16* dst = (colg < 8) ? D0 : D1;  // Qc2 : Kc2  [blh][s][c]
      const int h = colg & 7;
#pragma unroll
      for (int ni = 0; ni < 4; ni++) {
        const int c = ni * 16 + lr;
        const float bv = bias[(colg << 6) + c];
#pragma unroll
        for (int mi = 0; mi < 4; mi++) {
          const int r0 = by * 128 + wr * 64 + mi * 16 + lk * 4;
#pragma unroll
          for (int q = 0; q < 4; q++) {
            const int row = r0 + q;
            const int b = row >> 14, s = (row >> 8) & 63, l = row & 255;
            dst[(((size_t)(b * 256 + l) * 8 + h) * 64 + s) * 64 + c] = f2bf(acc[mi][ni][q] + bv);
          }
        }
      }
    } else {
      // V row-major [row][512]
#pragma unroll
      for (int ni = 0; ni < 4; ni++) {
        const int c512 = (bx - 8) * 128 + wc * 64 + ni * 16 + lr;
        const float bv = bias[1024 + c512];
#pragma unroll
        for (int mi = 0; mi < 4; mi++) {
          const int r0 = by * 128 + wr * 64 + mi * 16 + lk * 4;
#pragma unroll
          for (int q = 0; q < 4; q++)
            D2[(size_t)(r0 + q) * 512 + c512] = f2bf(acc[mi][ni][q] + bv);
        }
      }
    }
  }
}

// ---------------------------------------------------------------------------
// Row attention: block = (qt, bsh), 64 queries vs 256 keys. Wave owns 16 q
// rows x all 256 k (in-register softmax, 16-lane shfl). P overlays K buffer.
__global__ __launch_bounds__(256) void k_row_attn(
    const u16* __restrict__ Qh, const u16* __restrict__ Kh,
    const u16* __restrict__ Vth, u16* __restrict__ O) {
  __shared__ u16 KP[256 * 72];   // K stage [256][72]; later P [64][264]
  __shared__ u16 Vt[64 * 264];   // V^T stage [64][264]
  // swizzle: 4 sibling qt-blocks of one bsh land on the same XCD
  const int lin = blockIdx.x;
  const int qt = (lin >> 3) & 3;
  const int bsh = (lin & 7) + (lin >> 5) * 8;
  const int h = bsh & 7, bs = bsh >> 3;
  const int t = threadIdx.x, w = t >> 6, lane = t & 63, lr = lane & 15, lk = lane >> 4;
  const u16* kg = Kh + (size_t)bsh * 16384;
  const u16* vg = Vth + (size_t)bsh * 16384;
  // stage K: thread t stages the FULL 64-channel row t
#pragma unroll
  for (int u = 0; u < 8; u++)
    *reinterpret_cast<s16x8*>(&KP[t * 72 + u * 8]) =
        *reinterpret_cast<const s16x8*>(&kg[t * 64 + u * 8]);
#pragma unroll
  for (int i = 0; i < 8; i++) {
    const int id = i * 256 + t;
    const int r = id >> 5, ch = id & 31;
    *reinterpret_cast<s16x8*>(&Vt[r * 264 + ch * 8]) =
        *reinterpret_cast<const s16x8*>(&vg[r * 256 + ch * 8]);
  }
  const u16* qg = Qh + (size_t)bsh * 16384 + (size_t)(qt * 64 + w * 16 + lr) * 64 + lk * 8;
  const s16x8 aq0 = *reinterpret_cast<const s16x8*>(qg);
  const s16x8 aq1 = *reinterpret_cast<const s16x8*>(qg + 32);
  __syncthreads();

  f32x4 sc[16];
#pragma unroll
  for (int ni = 0; ni < 16; ni++) sc[ni] = fz4();
#pragma unroll
  for (int ni = 0; ni < 16; ni++) {
    const s16x8 b0 = *reinterpret_cast<const s16x8*>(&KP[(ni * 16 + lr) * 72 + lk * 8]);
    sc[ni] = __builtin_amdgcn_mfma_f32_16x16x32_bf16(aq0, b0, sc[ni], 0, 0, 0);
  }
#pragma unroll
  for (int ni = 0; ni < 16; ni++) {
    const s16x8 b1 = *reinterpret_cast<const s16x8*>(&KP[(ni * 16 + lr) * 72 + 32 + lk * 8]);
    sc[ni] = __builtin_amdgcn_mfma_f32_16x16x32_bf16(aq1, b1, sc[ni], 0, 0, 0);
  }
  // softmax: rows w*16 + lk*4 + qi, reduce over 16 frags + 16 lr lanes
  float mx[4], sm[4];
#pragma unroll
  for (int qi = 0; qi < 4; qi++) {
    float m = sc[0][qi];
#pragma unroll
    for (int ni = 1; ni < 16; ni++) m = fmaxf(m, sc[ni][qi]);
    mx[qi] = m;
  }
#pragma unroll
  for (int d = 1; d < 16; d <<= 1)
#pragma unroll
    for (int qi = 0; qi < 4; qi++) mx[qi] = fmaxf(mx[qi], __shfl_xor(mx[qi], d));
#pragma unroll
  for (int qi = 0; qi < 4; qi++) sm[qi] = 0.f;
#pragma unroll
  for (int ni = 0; ni < 16; ni++)
#pragma unroll
    for (int qi = 0; qi < 4; qi++) {
      const float p = __expf(sc[ni][qi] - mx[qi]);
      sc[ni][qi] = p;
      sm[qi] += p;
    }
#pragma unroll
  for (int d = 1; d < 16; d <<= 1)
#pragma unroll
    for (int qi = 0; qi < 4; qi++) sm[qi] += __shfl_xor(sm[qi], d);
  float inv[4];
#pragma unroll
  for (int qi = 0; qi < 4; qi++) inv[qi] = 1.f / sm[qi];
  __syncthreads();  // all waves done reading K
#pragma unroll
  for (int ni = 0; ni < 16; ni++)
#pragma unroll
    for (int qi = 0; qi < 4; qi++)
      KP[(w * 16 + lk * 4 + qi) * 264 + ni * 16 + lr] = f2bf(sc[ni][qi] * inv[qi]);
  __syncthreads();

  f32x4 o[4];
#pragma unroll
  for (int mi = 0; mi < 4; mi++) o[mi] = fz4();
#pragma unroll
  for (int ks = 0; ks < 8; ks++) {
    const s16x8 vb = *reinterpret_cast<const s16x8*>(&Vt[(w * 16 + lr) * 264 + ks * 32 + lk * 8]);
#pragma unroll
    for (int mi = 0; mi < 4; mi++) {
      const s16x8 pa = *reinterpret_cast<const s16x8*>(&KP[(mi * 16 + lr) * 264 + ks * 32 + lk * 8]);
      o[mi] = __builtin_amdgcn_mfma_f32_16x16x32_bf16(pa, vb, o[mi], 0, 0, 0);
    }
  }
  const size_t ob = (size_t)bs * 131072 + (size_t)qt * 64 * 512 + h * 64 + w * 16 + lr;
#pragma unroll
  for (int mi = 0; mi < 4; mi++)
#pragma unroll
    for (int qi = 0; qi < 4; qi++)
      O[ob + (size_t)(mi * 16 + lk * 4 + qi) * 512] = f2bf(o[mi][qi]);
}

// ---------------------------------------------------------------------------
// Column attention: per (b,l,h): QK^T (64x64,K=64) -> softmax over j -> PV.
// Q/K from per-(b,l,h) contiguous tiles; V from row-major qkv2.
__global__ __launch_bounds__(256) void k_col(
    const u16* __restrict__ Qc, const u16* __restrict__ Kc,
    const u16* __restrict__ V2, u16* __restrict__ O) {
  __shared__ u16 Qs[64][72];
  __shared__ u16 Ks[64][72];
  __shared__ u16 Pl[64][72];
  __shared__ u16 Vt[64][72];
  __shared__ float red[2][64][2];
  const int bid = blockIdx.x;
  const int h = bid & 7, bl = bid >> 3;
  const int l_ = bl & 255, b = bl >> 8;
  const size_t base = ((size_t)(b * 256 + l_) * 8 + h) * 4096;
  const int t = threadIdx.x;
  const int r = t >> 2, c0 = (t & 3) * 16;
  *reinterpret_cast<s16x8*>(&Qs[r][c0]) = *reinterpret_cast<const s16x8*>(&Qc[base + r * 64 + c0]);
  *reinterpret_cast<s16x8*>(&Qs[r][c0 + 8]) = *reinterpret_cast<const s16x8*>(&Qc[base + r * 64 + c0 + 8]);
  *reinterpret_cast<s16x8*>(&Ks[r][c0]) = *reinterpret_cast<const s16x8*>(&Kc[base + r * 64 + c0]);
  *reinterpret_cast<s16x8*>(&Ks[r][c0 + 8]) = *reinterpret_cast<const s16x8*>(&Kc[base + r * 64 + c0 + 8]);
  __syncthreads();
  const int w = t >> 6, l = t & 63, lr = l & 15, lk = l >> 4;
  const int wr = w >> 1, wc = w & 1;
  f32x4 acc[2][2];
#pragma unroll
  for (int i = 0; i < 2; i++)
#pragma unroll
    for (int jj = 0; jj < 2; jj++) acc[i][jj] = fz4();
#pragma unroll
  for (int ks = 0; ks < 2; ks++) {
    s16x8 aq[2], bq[2];
#pragma unroll
    for (int mi = 0; mi < 2; mi++)
      aq[mi] = *reinterpret_cast<const s16x8*>(&Qs[wr * 32 + mi * 16 + lr][ks * 32 + lk * 8]);
#pragma unroll
    for (int ni = 0; ni < 2; ni++)
      bq[ni] = *reinterpret_cast<const s16x8*>(&Ks[wc * 32 + ni * 16 + lr][ks * 32 + lk * 8]);
#pragma unroll
    for (int mi = 0; mi < 2; mi++)
#pragma unroll
      for (int ni = 0; ni < 2; ni++)
        acc[mi][ni] = __builtin_amdgcn_mfma_f32_16x16x32_bf16(aq[mi], bq[ni], acc[mi][ni], 0, 0, 0);
  }
  float mloc[2][4];
#pragma unroll
  for (int mi = 0; mi < 2; mi++)
#pragma unroll
    for (int q = 0; q < 4; q++) mloc[mi][q] = fmaxf(acc[mi][0][q], acc[mi][1][q]);
#pragma unroll
  for (int d = 1; d < 16; d <<= 1)
#pragma unroll
    for (int mi = 0; mi < 2; mi++)
#pragma unroll
      for (int q = 0; q < 4; q++)
        mloc[mi][q] = fmaxf(mloc[mi][q], __shfl_xor(mloc[mi][q], d));
  if (lr == 0)
#pragma unroll
    for (int mi = 0; mi < 2; mi++)
#pragma unroll
      for (int q = 0; q < 4; q++) red[0][wr * 32 + mi * 16 + lk * 4 + q][wc] = mloc[mi][q];
  __syncthreads();
  float mg[2][4], ss[2][4];
#pragma unroll
  for (int mi = 0; mi < 2; mi++)
#pragma unroll
    for (int q = 0; q < 4; q++) {
      const int r0 = wr * 32 + mi * 16 + lk * 4 + q;
      mg[mi][q] = fmaxf(red[0][r0][0], red[0][r0][1]);
      ss[mi][q] = 0.f;
    }
#pragma unroll
  for (int mi = 0; mi < 2; mi++)
#pragma unroll
    for (int ni = 0; ni < 2; ni++)
#pragma unroll
      for (int q = 0; q < 4; q++) {
        const float p = __expf(acc[mi][ni][q] - mg[mi][q]);
        acc[mi][ni][q] = p;
        ss[mi][q] += p;
      }
#pragma unroll
  for (int d = 1; d < 16; d <<= 1)
#pragma unroll
    for (int mi = 0; mi < 2; mi++)
#pragma unroll
      for (int q = 0; q < 4; q++) ss[mi][q] += __shfl_xor(ss[mi][q], d);
  if (lr == 0)
#pragma unroll
    for (int mi = 0; mi < 2; mi++)
#pragma unroll
      for (int q = 0; q < 4; q++) red[1][wr * 32 + mi * 16 + lk * 4 + q][wc] = ss[mi][q];
  __syncthreads();
#pragma unroll
  for (int mi = 0; mi < 2; mi++)
#pragma unroll
    for (int q = 0; q < 4; q++) {
      const int r0 = wr * 32 + mi * 16 + lk * 4 + q;
      const float inv = 1.f / (red[1][r0][0] + red[1][r0][1]);
#pragma unroll
      for (int ni = 0; ni < 2; ni++)
        Pl[r0][wc * 32 + ni * 16 + lr] = f2bf(acc[mi][ni][q] * inv);
    }
  __syncthreads();
  {
    const u16* vg = V2 + ((size_t)(b * 64) * 256 + l_) * 512 + h * 64;
#pragma unroll
    for (int u = 0; u < 4; u++) {
      U16x4 vv = *reinterpret_cast<const U16x4*>(&vg[(size_t)r * 131072 + c0 + u * 4]);
      Vt[c0 + u * 4 + 0][r] = vv.a; Vt[c0 + u * 4 + 1][r] = vv.b;
      Vt[c0 + u * 4 + 2][r] = vv.c; Vt[c0 + u * 4 + 3][r] = vv.d;
    }
  }
  __syncthreads();
  f32x4 acc2[2][2];
#pragma unroll
  for (int i = 0; i < 2; i++)
#pragma unroll
    for (int jj = 0; jj < 2; jj++) acc2[i][jj] = fz4();
#pragma unroll
  for (int ks = 0; ks < 2; ks++) {
    s16x8 ap[2], bp[2];
#pragma unroll
    for (int mi = 0; mi < 2; mi++)
      ap[mi] = *reinterpret_cast<const s16x8*>(&Pl[wr * 32 + mi * 16 + lr][ks * 32 + lk * 8]);
#pragma unroll
    for (int ni = 0; ni < 2; ni++)
      bp[ni] = *reinterpret_cast<const s16x8*>(&Vt[wc * 32 + ni * 16 + lr][ks * 32 + lk * 8]);
#pragma unroll
    for (int mi = 0; mi < 2; mi++)
#pragma unroll
      for (int ni = 0; ni < 2; ni++)
        acc2[mi][ni] = __builtin_amdgcn_mfma_f32_16x16x32_bf16(ap[mi], bp[ni], acc2[mi][ni], 0, 0, 0);
  }
  const size_t ob = ((size_t)b * 16384 + l_) * 512 + h * 64;
#pragma unroll
  for (int mi = 0; mi < 2; mi++)
#pragma unroll
    for (int ni = 0; ni < 2; ni++)
#pragma unroll
      for (int q = 0; q < 4; q++) {
        const int i = wr * 32 + mi * 16 + lk * 4 + q;
        const int cc = wc * 32 + ni * 16 + lr;
        O[ob + (size_t)i * 131072 + cc] = f2bf(acc2[mi][ni][q]);
      }
}

// ---------------------------------------------------------------------------
__global__ __launch_bounds__(256) void k_ln1(
    const float* __restrict__ xin, const u16* __restrict__ add,
    const float* __restrict__ g, const float* __restrict__ be,
    u16* __restrict__ outp) {
  const int w = threadIdx.x >> 6, l = threadIdx.x & 63;
  const size_t row = (size_t)blockIdx.x * 4 + w;
  const size_t o = row * 512 + l * 8;
  f32x4 x0 = *reinterpret_cast<const f32x4*>(xin + o);
  f32x4 x1 = *reinterpret_cast<const f32x4*>(xin + o + 4);
  U16x4 a0 = *reinterpret_cast<const U16x4*>(add + o);
  U16x4 a1 = *reinterpret_cast<const U16x4*>(add + o + 4);
  float v[8] = {x0.x + bf2f(a0.a), x0.y + bf2f(a0.b), x0.z + bf2f(a0.c), x0.w + bf2f(a0.d),
                x1.x + bf2f(a1.a), x1.y + bf2f(a1.b), x1.z + bf2f(a1.c), x1.w + bf2f(a1.d)};
  float s = 0.f, sq = 0.f;
#pragma unroll
  for (int i = 0; i < 8; i++) { s += v[i]; sq += v[i] * v[i]; }
#pragma unroll
  for (int d = 1; d < 64; d <<= 1) { s += __shfl_xor(s, d); sq += __shfl_xor(sq, d); }
  const float mu = s * (1.f / 512.f);
  const float var = sq * (1.f / 512.f) - mu * mu;
  const float rstd = rsqrtf(fmaxf(var, 0.f) + 1e-5f);
  U16x4 r0, r1;
  const float* gp = g + l * 8;
  const float* bp = be + l * 8;
  r0.a = f2bf((v[0] - mu) * rstd * gp[0] + bp[0]);
  r0.b = f2bf((v[1] - mu) * rstd * gp[1] + bp[1]);
  r0.c = f2bf((v[2] - mu) * rstd * gp[2] + bp[2]);
  r0.d = f2bf((v[3] - mu) * rstd * gp[3] + bp[3]);
  r1.a = f2bf((v[4] - mu) * rstd * gp[4] + bp[4]);
  r1.b = f2bf((v[5] - mu) * rstd * gp[5] + bp[5]);
  r1.c = f2bf((v[6] - mu) * rstd * gp[6] + bp[6]);
  r1.d = f2bf((v[7] - mu) * rstd * gp[7] + bp[7]);
  *reinterpret_cast<U16x4*>(outp + o) = r0;
  *reinterpret_cast<U16x4*>(outp + o + 4) = r1;
}

__global__ __launch_bounds__(256) void k_ln2(
    const u16* __restrict__ xin, const u16* __restrict__ add,
    const float* __restrict__ g, const float* __restrict__ be,
    float* __restrict__ outp) {
  const int w = threadIdx.x >> 6, l = threadIdx.x & 63;
  const size_t row = (size_t)blockIdx.x * 4 + w;
  const size_t o = row * 512 + l * 8;
  U16x4 x0 = *reinterpret_cast<const U16x4*>(xin + o);
  U16x4 x1 = *reinterpret_cast<const U16x4*>(xin + o + 4);
  U16x4 a0 = *reinterpret_cast<const U16x4*>(add + o);
  U16x4 a1 = *reinterpret_cast<const U16x4*>(add + o + 4);
  float v[8] = {bf2f(x0.a) + bf2f(a0.a), bf2f(x0.b) + bf2f(a0.b),
                bf2f(x0.c) + bf2f(a0.c), bf2f(x0.d) + bf2f(a0.d),
                bf2f(x1.a) + bf2f(a1.a), bf2f(x1.b) + bf2f(a1.b),
                bf2f(x1.c) + bf2f(a1.c), bf2f(x1.d) + bf2f(a1.d)};
  float s = 0.f, sq = 0.f;
#pragma unroll
  for (int i = 0; i < 8; i++) { s += v[i]; sq += v[i] * v[i]; }
#pragma unroll
  for (int d = 1; d < 64; d <<= 1) { s += __shfl_xor(s, d); sq += __shfl_xor(sq, d); }
  const float mu = s * (1.f / 512.f);
  const float var = sq * (1.f / 512.f) - mu * mu;
  const float rstd = rsqrtf(fmaxf(var, 0.f) + 1e-5f);
  f32x4 g0 = *reinterpret_cast<const f32x4*>(g + l * 8);
  f32x4 g1v = *reinterpret_cast<const f32x4*>(g + l * 8 + 4);
  f32x4 b0 = *reinterpret_cast<const f32x4*>(be + l * 8);
  f32x4 b1 = *reinterpret_cast<const f32x4*>(be + l * 8 + 4);
  f32x4 o0, o1;
  o0.x = (v[0] - mu) * rstd * g0.x + b0.x;
  o0.y = (v[1] - mu) * rstd * g0.y + b0.y;
  o0.z = (v[2] - mu) * rstd * g0.z + b0.z;
  o0.w = (v[3] - mu) * rstd * g0.w + b0.w;
  o1.x = (v[4] - mu) * rstd * g1v.x + b1.x;
  o1.y = (v[5] - mu) * rstd * g1v.y + b1.y;
  o1.z = (v[6] - mu) * rstd * g1v.z + b1.z;
  o1.w = (v[7] - mu) * rstd * g1v.w + b1.w;
  *reinterpret_cast<f32x4*>(outp + o) = o0;
  *reinterpret_cast<f32x4*>(outp + o + 4) = o1;
}

// ---------------------------------------------------------------------------
extern "C" void kernel_launch(void* const* d_in, const int* in_sizes, int n_in,
                              void* d_out, int out_size, void* d_ws, size_t ws_size,
                              hipStream_t stream) {
  const float* x     = (const float*)d_in[0];
  const float* w_row = (const float*)d_in[1];
  const float* b_row = (const float*)d_in[2];
  const float* w_col = (const float*)d_in[3];
  const float* b_col = (const float*)d_in[4];
  const float* g1    = (const float*)d_in[5];
  const float* be1   = (const float*)d_in[6];
  const float* g2    = (const float*)d_in[7];
  const float* be2   = (const float*)d_in[8];
  float* out = (float*)d_out;
  char* ws = (char*)d_ws;

  // workspace (bytes), total 202,899,456 (known to fit from round 2)
  u16* abf   = (u16*)(ws);                  // 33.5 MB  x bf16 / stage2: Qc2
  u16* Qh    = (u16*)(ws + 33554432);       // 33.5 MB  Qh / stage2: Kc2
  u16* Kh    = (u16*)(ws + 67108864);       // 33.5 MB  Kh / stage2: V2
  u16* Vth   = (u16*)(ws + 100663296);      // 33.5 MB  V^T per-head
  u16* attnb = (u16*)(ws + 134217728);      // 33.5 MB  attention out bf16
  u16* out1b = (u16*)(ws + 167772160);      // 33.5 MB  LN1 out bf16
  u16* wbf   = (u16*)(ws + 201326592);      //  1.5 MB  W bf16
  const size_t NEED = 202899456;
  if (ws_size < NEED) {
    hipMemsetAsync(d_out, 0, (size_t)out_size * 4, stream);
    return;
  }
  u16* Qc2 = abf;
  u16* Kc2 = Qh;
  u16* V2  = Kh;

  // ---- stage 1: row attention ----
  k_cvt<<<16384, 256, 0, stream>>>(x, abf, 4194304);
  k_cvt<<<768, 256, 0, stream>>>(w_row, wbf, 196608);
  k_gemm<0><<<3072, 256, 0, stream>>>(abf, wbf, b_row, Qh, Kh, Vth);
  k_row_attn<<<4096, 256, 0, stream>>>(Qh, Kh, Vth, attnb);
  k_ln1<<<8192, 256, 0, stream>>>(x, attnb, g1, be1, out1b);

  // ---- stage 2: column attention ----
  k_cvt<<<768, 256, 0, stream>>>(w_col, wbf, 196608);
  k_gemm<1><<<3072, 256, 0, stream>>>(out1b, wbf, b_col, Qc2, Kc2, V2);
  k_col<<<4096, 256, 0, stream>>>(Qc2, Kc2, V2, attnb);
  k_ln2<<<8192, 256, 0, stream>>>(out1b, attnb, g2, be2, out);
}

// Round 9
// 411.483 us; speedup vs baseline: 1.3087x; 1.0145x over previous
//
#include <hip/hip_runtime.h>

typedef unsigned short u16;
typedef unsigned int u32;
typedef float f32x4 __attribute__((ext_vector_type(4)));
typedef short s16x8 __attribute__((ext_vector_type(8)));

struct alignas(8) U16x4 { u16 a, b, c, d; };

#define DEV static __device__ __forceinline__

DEV u16 f2bf(float f) {
  u32 x = __float_as_uint(f);
  x += 0x7fffu + ((x >> 16) & 1u);
  return (u16)(x >> 16);
}
DEV float bf2f(u16 u) { return __uint_as_float(((u32)u) << 16); }
DEV f32x4 fz4() { f32x4 z = {0.f, 0.f, 0.f, 0.f}; return z; }

// async global->LDS, 16B per lane; lds dest must be wave-uniform base (+lane*16 by HW)
DEV void gl16(const u16* g, u16* l) {
  __builtin_amdgcn_global_load_lds(
      (const __attribute__((address_space(1))) u32*)g,
      (__attribute__((address_space(3))) u32*)l, 16, 0, 0);
}

// Problem constants: B=2, S=64, L=256, H=8, C=64, D=512, 3D=1536, M=32768

// ---------------------------------------------------------------------------
__global__ __launch_bounds__(256) void k_cvt(const float* __restrict__ in,
                                             u16* __restrict__ outp, int n4) {
  int i = blockIdx.x * 256 + threadIdx.x;
  if (i < n4) {
    f32x4 v = reinterpret_cast<const f32x4*>(in)[i];
    U16x4 r = {f2bf(v.x), f2bf(v.y), f2bf(v.z), f2bf(v.w)};
    reinterpret_cast<U16x4*>(outp)[i] = r;
  }
}

// ---------------------------------------------------------------------------
// GEMM C[M,1536] = A[M,512]*W[1536,512]^T + bias. 128x128 tile, BK=32.
// T4 pipeline, RACE-FIXED (round-8): per K-step
//   STAGE(kt+1) ; vmcnt(4) [own kt loads done] ; s_barrier [ALL kt loads
//   certified] ; COMPUTE(cur) ; s_barrier [WAR: cur may be overwritten next].
// Group kt+1 loads stay in flight across both barriers (counted wait, not 0).
// MODE 0 (stage 1): Q/K -> per-head [bsh][l][c]; V -> TRANSPOSED [bsh][c][l]
//   via MFMA operand swap. MODE 1: Q/K -> [blh][s][c]; V row-major.
template<int MODE>
__global__ __launch_bounds__(256) void k_gemm(
    const u16* __restrict__ A, const u16* __restrict__ W,
    const float* __restrict__ bias,
    u16* __restrict__ D0, u16* __restrict__ D1, u16* __restrict__ D2) {
  __shared__ u16 Sg[16384];  // dbuf: buf b at b*8192: A[128][32] @+0, W @+4096
  const int lin = blockIdx.x;
  const int j = lin >> 3, xcd = lin & 7;
  const int bx = j % 12;
  const int by = xcd * 32 + j / 12;
  const int t = threadIdx.x;
  const int w = t >> 6, lane = t & 63, lr = lane & 15, lk = lane >> 4;
  const int wr = w >> 1, wc = w & 1;
  const bool vblk = (bx >= 8) && (MODE == 0);

  f32x4 acc[4][4];
#pragma unroll
  for (int i = 0; i < 4; i++)
#pragma unroll
    for (int jj = 0; jj < 4; jj++) acc[i][jj] = fz4();

  const int srow = w * 32 + (lane >> 2);
  const int scol = (lane & 3) * 8;
  const u16* Ap = A + (size_t)(by * 128 + srow) * 512 + scol;
  const u16* Wp = W + (size_t)(bx * 128 + srow) * 512 + scol;
  const int wb = w * 1024;  // wave-local staging base (u16)

#define STAGE(kt_, buf_)                                            \
  {                                                                 \
    const int k_ = (kt_) * 32;                                      \
    gl16(Ap + k_, &Sg[(buf_) + wb]);                                \
    gl16(Ap + k_ + 16 * 512, &Sg[(buf_) + wb + 512]);               \
    gl16(Wp + k_, &Sg[(buf_) + 4096 + wb]);                         \
    gl16(Wp + k_ + 16 * 512, &Sg[(buf_) + 4096 + wb + 512]);        \
  }

#define COMPUTE(cur_)                                                             \
  {                                                                               \
    s16x8 aq[4], bq[4];                                                           \
    _Pragma("unroll")                                                             \
    for (int mi = 0; mi < 4; mi++)                                                \
      aq[mi] = *reinterpret_cast<const s16x8*>(                                   \
          &Sg[(cur_) + (wr * 64 + mi * 16 + lr) * 32 + lk * 8]);                  \
    _Pragma("unroll")                                                             \
    for (int ni = 0; ni < 4; ni++)                                                \
      bq[ni] = *reinterpret_cast<const s16x8*>(                                   \
          &Sg[(cur_) + 4096 + (wc * 64 + ni * 16 + lr) * 32 + lk * 8]);           \
    if (!vblk) {                                                                  \
      _Pragma("unroll")                                                           \
      for (int mi = 0; mi < 4; mi++)                                              \
        _Pragma("unroll")                                                         \
        for (int ni = 0; ni < 4; ni++)                                            \
          acc[mi][ni] = __builtin_amdgcn_mfma_f32_16x16x32_bf16(                  \
              aq[mi], bq[ni], acc[mi][ni], 0, 0, 0);                              \
    } else {                                                                      \
      _Pragma("unroll")                                                           \
      for (int mi = 0; mi < 4; mi++)                                              \
        _Pragma("unroll")                                                         \
        for (int ni = 0; ni < 4; ni++)                                            \
          acc[mi][ni] = __builtin_amdgcn_mfma_f32_16x16x32_bf16(                  \
              bq[ni], aq[mi], acc[mi][ni], 0, 0, 0);                              \
    }                                                                             \
  }

  // stage kt=0 into buffer 0 (no barrier needed yet: certification happens
  // via each wave's vmcnt + the pre-compute barrier inside the loop)
  STAGE(0, 0)

  for (int kt = 0; kt < 15; ++kt) {
    const int cur = (kt & 1) * 8192;
    const int nxt = 8192 - cur;
    STAGE(kt + 1, nxt)                                 // 8 loads outstanding
    asm volatile("s_waitcnt vmcnt(4)" ::: "memory");   // own group kt landed
    asm volatile("s_barrier" ::: "memory");            // ALL groups kt landed
    COMPUTE(cur)
    asm volatile("s_barrier" ::: "memory");            // WAR: cur reusable
  }
  // kt=15: nothing left to stage; drain fully, certify, compute
  asm volatile("s_waitcnt vmcnt(0)" ::: "memory");
  asm volatile("s_barrier" ::: "memory");
  COMPUTE(8192)  // kt=15 is odd -> buffer 1

#undef STAGE
#undef COMPUTE

  const int colg = bx * 2 + wc;  // col>>6
  if (MODE == 0) {
    const int bs = by >> 1;
    if (!vblk) {
      u16* dst = (colg < 8) ? D0 : D1;  // Qh : Kh
      const int h = colg & 7;
      const size_t hb = (size_t)(bs * 8 + h) * 16384;
#pragma unroll
      for (int ni = 0; ni < 4; ni++) {
        const int c = ni * 16 + lr;
        const float bv = bias[(colg << 6) + c];
#pragma unroll
        for (int mi = 0; mi < 4; mi++) {
          const int l0 = (by & 1) * 128 + wr * 64 + mi * 16 + lk * 4;
#pragma unroll
          for (int q = 0; q < 4; q++)
            dst[hb + (size_t)(l0 + q) * 64 + c] = f2bf(acc[mi][ni][q] + bv);
        }
      }
    } else {
      const int h = colg & 7;
      const size_t hb = (size_t)(bs * 8 + h) * 16384;
#pragma unroll
      for (int ni = 0; ni < 4; ni++) {
        const int c0 = ni * 16 + lk * 4;
        const f32x4 bv4 = *reinterpret_cast<const f32x4*>(&bias[(colg << 6) + c0]);
#pragma unroll
        for (int mi = 0; mi < 4; mi++) {
          const int l = (by & 1) * 128 + wr * 64 + mi * 16 + lr;
#pragma unroll
          for (int q = 0; q < 4; q++)
            D2[hb + (size_t)(c0 + q) * 256 + l] = f2bf(acc[mi][ni][q] + bv4[q]);
        }
      }
    }
  } else {
    if (colg < 16) {
      u16* dst = (colg < 8) ? D0 : D1;  // Qc2 : Kc2  [blh][s][c]
      const int h = colg & 7;
#pragma unroll
      for (int ni = 0; ni < 4; ni++) {
        const int c = ni * 16 + lr;
        const float bv = bias[(colg << 6) + c];
#pragma unroll
        for (int mi = 0; mi < 4; mi++) {
          const int r0 = by * 128 + wr * 64 + mi * 16 + lk * 4;
#pragma unroll
          for (int q = 0; q < 4; q++) {
            const int row = r0 + q;
            const int b = row >> 14, s = (row >> 8) & 63, l = row & 255;
            dst[(((size_t)(b * 256 + l) * 8 + h) * 64 + s) * 64 + c] = f2bf(acc[mi][ni][q] + bv);
          }
        }
      }
    } else {
      // V row-major [row][512]
#pragma unroll
      for (int ni = 0; ni < 4; ni++) {
        const int c512 = (bx - 8) * 128 + wc * 64 + ni * 16 + lr;
        const float bv = bias[1024 + c512];
#pragma unroll
        for (int mi = 0; mi < 4; mi++) {
          const int r0 = by * 128 + wr * 64 + mi * 16 + lk * 4;
#pragma unroll
          for (int q = 0; q < 4; q++)
            D2[(size_t)(r0 + q) * 512 + c512] = f2bf(acc[mi][ni][q] + bv);
        }
      }
    }
  }
}

// ---------------------------------------------------------------------------
// Row attention: block = (qt, bsh), 64 queries vs 256 keys. Wave owns 16 q
// rows x all 256 k (in-register softmax, 16-lane shfl). P overlays K buffer.
__global__ __launch_bounds__(256) void k_row_attn(
    const u16* __restrict__ Qh, const u16* __restrict__ Kh,
    const u16* __restrict__ Vth, u16* __restrict__ O) {
  __shared__ u16 KP[256 * 72];   // K stage [256][72]; later P [64][264]
  __shared__ u16 Vt[64 * 264];   // V^T stage [64][264]
  const int lin = blockIdx.x;
  const int qt = (lin >> 3) & 3;
  const int bsh = (lin & 7) + (lin >> 5) * 8;
  const int h = bsh & 7, bs = bsh >> 3;
  const int t = threadIdx.x, w = t >> 6, lane = t & 63, lr = lane & 15, lk = lane >> 4;
  const u16* kg = Kh + (size_t)bsh * 16384;
  const u16* vg = Vth + (size_t)bsh * 16384;
#pragma unroll
  for (int u = 0; u < 8; u++)
    *reinterpret_cast<s16x8*>(&KP[t * 72 + u * 8]) =
        *reinterpret_cast<const s16x8*>(&kg[t * 64 + u * 8]);
#pragma unroll
  for (int i = 0; i < 8; i++) {
    const int id = i * 256 + t;
    const int r = id >> 5, ch = id & 31;
    *reinterpret_cast<s16x8*>(&Vt[r * 264 + ch * 8]) =
        *reinterpret_cast<const s16x8*>(&vg[r * 256 + ch * 8]);
  }
  const u16* qg = Qh + (size_t)bsh * 16384 + (size_t)(qt * 64 + w * 16 + lr) * 64 + lk * 8;
  const s16x8 aq0 = *reinterpret_cast<const s16x8*>(qg);
  const s16x8 aq1 = *reinterpret_cast<const s16x8*>(qg + 32);
  __syncthreads();

  f32x4 sc[16];
#pragma unroll
  for (int ni = 0; ni < 16; ni++) sc[ni] = fz4();
#pragma unroll
  for (int ni = 0; ni < 16; ni++) {
    const s16x8 b0 = *reinterpret_cast<const s16x8*>(&KP[(ni * 16 + lr) * 72 + lk * 8]);
    sc[ni] = __builtin_amdgcn_mfma_f32_16x16x32_bf16(aq0, b0, sc[ni], 0, 0, 0);
  }
#pragma unroll
  for (int ni = 0; ni < 16; ni++) {
    const s16x8 b1 = *reinterpret_cast<const s16x8*>(&KP[(ni * 16 + lr) * 72 + 32 + lk * 8]);
    sc[ni] = __builtin_amdgcn_mfma_f32_16x16x32_bf16(aq1, b1, sc[ni], 0, 0, 0);
  }
  // softmax: rows w*16 + lk*4 + qi, reduce over 16 frags + 16 lr lanes
  float mx[4], sm[4];
#pragma unroll
  for (int qi = 0; qi < 4; qi++) {
    float m = sc[0][qi];
#pragma unroll
    for (int ni = 1; ni < 16; ni++) m = fmaxf(m, sc[ni][qi]);
    mx[qi] = m;
  }
#pragma unroll
  for (int d = 1; d < 16; d <<= 1)
#pragma unroll
    for (int qi = 0; qi < 4; qi++) mx[qi] = fmaxf(mx[qi], __shfl_xor(mx[qi], d));
#pragma unroll
  for (int qi = 0; qi < 4; qi++) sm[qi] = 0.f;
#pragma unroll
  for (int ni = 0; ni < 16; ni++)
#pragma unroll
    for (int qi = 0; qi < 4; qi++) {
      const float p = __expf(sc[ni][qi] - mx[qi]);
      sc[ni][qi] = p;
      sm[qi] += p;
    }
#pragma unroll
  for (int d = 1; d < 16; d <<= 1)
#pragma unroll
    for (int qi = 0; qi < 4; qi++) sm[qi] += __shfl_xor(sm[qi], d);
  float inv[4];
#pragma unroll
  for (int qi = 0; qi < 4; qi++) inv[qi] = 1.f / sm[qi];
  __syncthreads();  // all waves done reading K
#pragma unroll
  for (int ni = 0; ni < 16; ni++)
#pragma unroll
    for (int qi = 0; qi < 4; qi++)
      KP[(w * 16 + lk * 4 + qi) * 264 + ni * 16 + lr] = f2bf(sc[ni][qi] * inv[qi]);
  __syncthreads();

  f32x4 o[4];
#pragma unroll
  for (int mi = 0; mi < 4; mi++) o[mi] = fz4();
#pragma unroll
  for (int ks = 0; ks < 8; ks++) {
    const s16x8 vb = *reinterpret_cast<const s16x8*>(&Vt[(w * 16 + lr) * 264 + ks * 32 + lk * 8]);
#pragma unroll
    for (int mi = 0; mi < 4; mi++) {
      const s16x8 pa = *reinterpret_cast<const s16x8*>(&KP[(mi * 16 + lr) * 264 + ks * 32 + lk * 8]);
      o[mi] = __builtin_amdgcn_mfma_f32_16x16x32_bf16(pa, vb, o[mi], 0, 0, 0);
    }
  }
  const size_t ob = (size_t)bs * 131072 + (size_t)qt * 64 * 512 + h * 64 + w * 16 + lr;
#pragma unroll
  for (int mi = 0; mi < 4; mi++)
#pragma unroll
    for (int qi = 0; qi < 4; qi++)
      O[ob + (size_t)(mi * 16 + lk * 4 + qi) * 512] = f2bf(o[mi][qi]);
}

// ---------------------------------------------------------------------------
// Column attention: per (b,l,h): QK^T (64x64,K=64) -> softmax over j -> PV.
__global__ __launch_bounds__(256) void k_col(
    const u16* __restrict__ Qc, const u16* __restrict__ Kc,
    const u16* __restrict__ V2, u16* __restrict__ O) {
  __shared__ u16 Qs[64][72];
  __shared__ u16 Ks[64][72];
  __shared__ u16 Pl[64][72];
  __shared__ u16 Vt[64][72];
  __shared__ float red[2][64][2];
  const int bid = blockIdx.x;
  const int h = bid & 7, bl = bid >> 3;
  const int l_ = bl & 255, b = bl >> 8;
  const size_t base = ((size_t)(b * 256 + l_) * 8 + h) * 4096;
  const int t = threadIdx.x;
  const int r = t >> 2, c0 = (t & 3) * 16;
  *reinterpret_cast<s16x8*>(&Qs[r][c0]) = *reinterpret_cast<const s16x8*>(&Qc[base + r * 64 + c0]);
  *reinterpret_cast<s16x8*>(&Qs[r][c0 + 8]) = *reinterpret_cast<const s16x8*>(&Qc[base + r * 64 + c0 + 8]);
  *reinterpret_cast<s16x8*>(&Ks[r][c0]) = *reinterpret_cast<const s16x8*>(&Kc[base + r * 64 + c0]);
  *reinterpret_cast<s16x8*>(&Ks[r][c0 + 8]) = *reinterpret_cast<const s16x8*>(&Kc[base + r * 64 + c0 + 8]);
  __syncthreads();
  const int w = t >> 6, l = t & 63, lr = l & 15, lk = l >> 4;
  const int wr = w >> 1, wc = w & 1;
  f32x4 acc[2][2];
#pragma unroll
  for (int i = 0; i < 2; i++)
#pragma unroll
    for (int jj = 0; jj < 2; jj++) acc[i][jj] = fz4();
#pragma unroll
  for (int ks = 0; ks < 2; ks++) {
    s16x8 aq[2], bq[2];
#pragma unroll
    for (int mi = 0; mi < 2; mi++)
      aq[mi] = *reinterpret_cast<const s16x8*>(&Qs[wr * 32 + mi * 16 + lr][ks * 32 + lk * 8]);
#pragma unroll
    for (int ni = 0; ni < 2; ni++)
      bq[ni] = *reinterpret_cast<const s16x8*>(&Ks[wc * 32 + ni * 16 + lr][ks * 32 + lk * 8]);
#pragma unroll
    for (int mi = 0; mi < 2; mi++)
#pragma unroll
      for (int ni = 0; ni < 2; ni++)
        acc[mi][ni] = __builtin_amdgcn_mfma_f32_16x16x32_bf16(aq[mi], bq[ni], acc[mi][ni], 0, 0, 0);
  }
  float mloc[2][4];
#pragma unroll
  for (int mi = 0; mi < 2; mi++)
#pragma unroll
    for (int q = 0; q < 4; q++) mloc[mi][q] = fmaxf(acc[mi][0][q], acc[mi][1][q]);
#pragma unroll
  for (int d = 1; d < 16; d <<= 1)
#pragma unroll
    for (int mi = 0; mi < 2; mi++)
#pragma unroll
      for (int q = 0; q < 4; q++)
        mloc[mi][q] = fmaxf(mloc[mi][q], __shfl_xor(mloc[mi][q], d));
  if (lr == 0)
#pragma unroll
    for (int mi = 0; mi < 2; mi++)
#pragma unroll
      for (int q = 0; q < 4; q++) red[0][wr * 32 + mi * 16 + lk * 4 + q][wc] = mloc[mi][q];
  __syncthreads();
  float mg[2][4], ss[2][4];
#pragma unroll
  for (int mi = 0; mi < 2; mi++)
#pragma unroll
    for (int q = 0; q < 4; q++) {
      const int r0 = wr * 32 + mi * 16 + lk * 4 + q;
      mg[mi][q] = fmaxf(red[0][r0][0], red[0][r0][1]);
      ss[mi][q] = 0.f;
    }
#pragma unroll
  for (int mi = 0; mi < 2; mi++)
#pragma unroll
    for (int ni = 0; ni < 2; ni++)
#pragma unroll
      for (int q = 0; q < 4; q++) {
        const float p = __expf(acc[mi][ni][q] - mg[mi][q]);
        acc[mi][ni][q] = p;
        ss[mi][q] += p;
      }
#pragma unroll
  for (int d = 1; d < 16; d <<= 1)
#pragma unroll
    for (int mi = 0; mi < 2; mi++)
#pragma unroll
      for (int q = 0; q < 4; q++) ss[mi][q] += __shfl_xor(ss[mi][q], d);
  if (lr == 0)
#pragma unroll
    for (int mi = 0; mi < 2; mi++)
#pragma unroll
      for (int q = 0; q < 4; q++) red[1][wr * 32 + mi * 16 + lk * 4 + q][wc] = ss[mi][q];
  __syncthreads();
#pragma unroll
  for (int mi = 0; mi < 2; mi++)
#pragma unroll
    for (int q = 0; q < 4; q++) {
      const int r0 = wr * 32 + mi * 16 + lk * 4 + q;
      const float inv = 1.f / (red[1][r0][0] + red[1][r0][1]);
#pragma unroll
      for (int ni = 0; ni < 2; ni++)
        Pl[r0][wc * 32 + ni * 16 + lr] = f2bf(acc[mi][ni][q] * inv);
    }
  __syncthreads();
  {
    const u16* vg = V2 + ((size_t)(b * 64) * 256 + l_) * 512 + h * 64;
#pragma unroll
    for (int u = 0; u < 4; u++) {
      U16x4 vv = *reinterpret_cast<const U16x4*>(&vg[(size_t)r * 131072 + c0 + u * 4]);
      Vt[c0 + u * 4 + 0][r] = vv.a; Vt[c0 + u * 4 + 1][r] = vv.b;
      Vt[c0 + u * 4 + 2][r] = vv.c; Vt[c0 + u * 4 + 3][r] = vv.d;
    }
  }
  __syncthreads();
  f32x4 acc2[2][2];
#pragma unroll
  for (int i = 0; i < 2; i++)
#pragma unroll
    for (int jj = 0; jj < 2; jj++) acc2[i][jj] = fz4();
#pragma unroll
  for (int ks = 0; ks < 2; ks++) {
    s16x8 ap[2], bp[2];
#pragma unroll
    for (int mi = 0; mi < 2; mi++)
      ap[mi] = *reinterpret_cast<const s16x8*>(&Pl[wr * 32 + mi * 16 + lr][ks * 32 + lk * 8]);
#pragma unroll
    for (int ni = 0; ni < 2; ni++)
      bp[ni] = *reinterpret_cast<const s16x8*>(&Vt[wc * 32 + ni * 16 + lr][ks * 32 + lk * 8]);
#pragma unroll
    for (int mi = 0; mi < 2; mi++)
#pragma unroll
      for (int ni = 0; ni < 2; ni++)
        acc2[mi][ni] = __builtin_amdgcn_mfma_f32_16x16x32_bf16(ap[mi], bp[ni], acc2[mi][ni], 0, 0, 0);
  }
  const size_t ob = ((size_t)b * 16384 + l_) * 512 + h * 64;
#pragma unroll
  for (int mi = 0; mi < 2; mi++)
#pragma unroll
    for (int ni = 0; ni < 2; ni++)
#pragma unroll
      for (int q = 0; q < 4; q++) {
        const int i = wr * 32 + mi * 16 + lk * 4 + q;
        const int cc = wc * 32 + ni * 16 + lr;
        O[ob + (size_t)i * 131072 + cc] = f2bf(acc2[mi][ni][q]);
      }
}

// ---------------------------------------------------------------------------
__global__ __launch_bounds__(256) void k_ln1(
    const float* __restrict__ xin, const u16* __restrict__ add,
    const float* __restrict__ g, const float* __restrict__ be,
    u16* __restrict__ outp) {
  const int w = threadIdx.x >> 6, l = threadIdx.x & 63;
  const size_t row = (size_t)blockIdx.x * 4 + w;
  const size_t o = row * 512 + l * 8;
  f32x4 x0 = *reinterpret_cast<const f32x4*>(xin + o);
  f32x4 x1 = *reinterpret_cast<const f32x4*>(xin + o + 4);
  U16x4 a0 = *reinterpret_cast<const U16x4*>(add + o);
  U16x4 a1 = *reinterpret_cast<const U16x4*>(add + o + 4);
  float v[8] = {x0.x + bf2f(a0.a), x0.y + bf2f(a0.b), x0.z + bf2f(a0.c), x0.w + bf2f(a0.d),
                x1.x + bf2f(a1.a), x1.y + bf2f(a1.b), x1.z + bf2f(a1.c), x1.w + bf2f(a1.d)};
  float s = 0.f, sq = 0.f;
#pragma unroll
  for (int i = 0; i < 8; i++) { s += v[i]; sq += v[i] * v[i]; }
#pragma unroll
  for (int d = 1; d < 64; d <<= 1) { s += __shfl_xor(s, d); sq += __shfl_xor(sq, d); }
  const float mu = s * (1.f / 512.f);
  const float var = sq * (1.f / 512.f) - mu * mu;
  const float rstd = rsqrtf(fmaxf(var, 0.f) + 1e-5f);
  U16x4 r0, r1;
  const float* gp = g + l * 8;
  const float* bp = be + l * 8;
  r0.a = f2bf((v[0] - mu) * rstd * gp[0] + bp[0]);
  r0.b = f2bf((v[1] - mu) * rstd * gp[1] + bp[1]);
  r0.c = f2bf((v[2] - mu) * rstd * gp[2] + bp[2]);
  r0.d = f2bf((v[3] - mu) * rstd * gp[3] + bp[3]);
  r1.a = f2bf((v[4] - mu) * rstd * gp[4] + bp[4]);
  r1.b = f2bf((v[5] - mu) * rstd * gp[5] + bp[5]);
  r1.c = f2bf((v[6] - mu) * rstd * gp[6] + bp[6]);
  r1.d = f2bf((v[7] - mu) * rstd * gp[7] + bp[7]);
  *reinterpret_cast<U16x4*>(outp + o) = r0;
  *reinterpret_cast<U16x4*>(outp + o + 4) = r1;
}

__global__ __launch_bounds__(256) void k_ln2(
    const u16* __restrict__ xin, const u16* __restrict__ add,
    const float* __restrict__ g, const float* __restrict__ be,
    float* __restrict__ outp) {
  const int w = threadIdx.x >> 6, l = threadIdx.x & 63;
  const size_t row = (size_t)blockIdx.x * 4 + w;
  const size_t o = row * 512 + l * 8;
  U16x4 x0 = *reinterpret_cast<const U16x4*>(xin + o);
  U16x4 x1 = *reinterpret_cast<const U16x4*>(xin + o + 4);
  U16x4 a0 = *reinterpret_cast<const U16x4*>(add + o);
  U16x4 a1 = *reinterpret_cast<const U16x4*>(add + o + 4);
  float v[8] = {bf2f(x0.a) + bf2f(a0.a), bf2f(x0.b) + bf2f(a0.b),
                bf2f(x0.c) + bf2f(a0.c), bf2f(x0.d) + bf2f(a0.d),
                bf2f(x1.a) + bf2f(a1.a), bf2f(x1.b) + bf2f(a1.b),
                bf2f(x1.c) + bf2f(a1.c), bf2f(x1.d) + bf2f(a1.d)};
  float s = 0.f, sq = 0.f;
#pragma unroll
  for (int i = 0; i < 8; i++) { s += v[i]; sq += v[i] * v[i]; }
#pragma unroll
  for (int d = 1; d < 64; d <<= 1) { s += __shfl_xor(s, d); sq += __shfl_xor(sq, d); }
  const float mu = s * (1.f / 512.f);
  const float var = sq * (1.f / 512.f) - mu * mu;
  const float rstd = rsqrtf(fmaxf(var, 0.f) + 1e-5f);
  f32x4 g0 = *reinterpret_cast<const f32x4*>(g + l * 8);
  f32x4 g1v = *reinterpret_cast<const f32x4*>(g + l * 8 + 4);
  f32x4 b0 = *reinterpret_cast<const f32x4*>(be + l * 8);
  f32x4 b1 = *reinterpret_cast<const f32x4*>(be + l * 8 + 4);
  f32x4 o0, o1;
  o0.x = (v[0] - mu) * rstd * g0.x + b0.x;
  o0.y = (v[1] - mu) * rstd * g0.y + b0.y;
  o0.z = (v[2] - mu) * rstd * g0.z + b0.z;
  o0.w = (v[3] - mu) * rstd * g0.w + b0.w;
  o1.x = (v[4] - mu) * rstd * g1v.x + b1.x;
  o1.y = (v[5] - mu) * rstd * g1v.y + b1.y;
  o1.z = (v[6] - mu) * rstd * g1v.z + b1.z;
  o1.w = (v[7] - mu) * rstd * g1v.w + b1.w;
  *reinterpret_cast<f32x4*>(outp + o) = o0;
  *reinterpret_cast<f32x4*>(outp + o + 4) = o1;
}

// ---------------------------------------------------------------------------
extern "C" void kernel_launch(void* const* d_in, const int* in_sizes, int n_in,
                              void* d_out, int out_size, void* d_ws, size_t ws_size,
                              hipStream_t stream) {
  const float* x     = (const float*)d_in[0];
  const float* w_row = (const float*)d_in[1];
  const float* b_row = (const float*)d_in[2];
  const float* w_col = (const float*)d_in[3];
  const float* b_col = (const float*)d_in[4];
  const float* g1    = (const float*)d_in[5];
  const float* be1   = (const float*)d_in[6];
  const float* g2    = (const float*)d_in[7];
  const float* be2   = (const float*)d_in[8];
  float* out = (float*)d_out;
  char* ws = (char*)d_ws;

  // workspace (bytes), total 202,899,456
  u16* abf   = (u16*)(ws);                  // 33.5 MB  x bf16 / stage2: Qc2
  u16* Qh    = (u16*)(ws + 33554432);       // 33.5 MB  Qh / stage2: Kc2
  u16* Kh    = (u16*)(ws + 67108864);       // 33.5 MB  Kh / stage2: V2
  u16* Vth   = (u16*)(ws + 100663296);      // 33.5 MB  V^T per-head
  u16* attnb = (u16*)(ws + 134217728);      // 33.5 MB  attention out bf16
  u16* out1b = (u16*)(ws + 167772160);      // 33.5 MB  LN1 out bf16
  u16* wbf   = (u16*)(ws + 201326592);      //  1.5 MB  W bf16
  const size_t NEED = 202899456;
  if (ws_size < NEED) {
    hipMemsetAsync(d_out, 0, (size_t)out_size * 4, stream);
    return;
  }
  u16* Qc2 = abf;
  u16* Kc2 = Qh;
  u16* V2  = Kh;

  // ---- stage 1: row attention ----
  k_cvt<<<16384, 256, 0, stream>>>(x, abf, 4194304);
  k_cvt<<<768, 256, 0, stream>>>(w_row, wbf, 196608);
  k_gemm<0><<<3072, 256, 0, stream>>>(abf, wbf, b_row, Qh, Kh, Vth);
  k_row_attn<<<4096, 256, 0, stream>>>(Qh, Kh, Vth, attnb);
  k_ln1<<<8192, 256, 0, stream>>>(x, attnb, g1, be1, out1b);

  // ---- stage 2: column attention ----
  k_cvt<<<768, 256, 0, stream>>>(w_col, wbf, 196608);
  k_gemm<1><<<3072, 256, 0, stream>>>(out1b, wbf, b_col, Qc2, Kc2, V2);
  k_col<<<4096, 256, 0, stream>>>(Qc2, Kc2, V2, attnb);
  k_ln2<<<8192, 256, 0, stream>>>(out1b, attnb, g2, be2, out);
}

// Round 10
// 380.033 us; speedup vs baseline: 1.4170x; 1.0828x over previous
//
#include <hip/hip_runtime.h>

typedef unsigned short u16;
typedef unsigned int u32;
typedef float f32x4 __attribute__((ext_vector_type(4)));
typedef short s16x8 __attribute__((ext_vector_type(8)));

struct alignas(8) U16x4 { u16 a, b, c, d; };

#define DEV static __device__ __forceinline__

DEV u16 f2bf(float f) {
  u32 x = __float_as_uint(f);
  x += 0x7fffu + ((x >> 16) & 1u);
  return (u16)(x >> 16);
}
DEV float bf2f(u16 u) { return __uint_as_float(((u32)u) << 16); }
DEV f32x4 fz4() { f32x4 z = {0.f, 0.f, 0.f, 0.f}; return z; }

// async global->LDS, 16B per lane; lds dest must be wave-uniform base (+lane*16 by HW)
DEV void gl16(const u16* g, u16* l) {
  __builtin_amdgcn_global_load_lds(
      (const __attribute__((address_space(1))) u32*)g,
      (__attribute__((address_space(3))) u32*)l, 16, 0, 0);
}

// Problem constants: B=2, S=64, L=256, H=8, C=64, D=512, 3D=1536, M=32768

// ---------------------------------------------------------------------------
__global__ __launch_bounds__(256) void k_cvt(const float* __restrict__ in,
                                             u16* __restrict__ outp, int n4) {
  int i = blockIdx.x * 256 + threadIdx.x;
  if (i < n4) {
    f32x4 v = reinterpret_cast<const f32x4*>(in)[i];
    U16x4 r = {f2bf(v.x), f2bf(v.y), f2bf(v.z), f2bf(v.w)};
    reinterpret_cast<U16x4*>(outp)[i] = r;
  }
}

// ---------------------------------------------------------------------------
// GEMM C[M,1536] = A[M,512]*W[1536,512]^T + bias. 128x128 tile, BK=32.
// Round-9: TRIPLE-buffered, depth-2 prefetch. Steady state keeps groups
// kt..kt+2 (12 loads) in flight; vmcnt(8) certifies own group kt, then
// s_barrier makes it collective. Tile kt+2 lands ~2 compute phases before
// use -> L2 latency (~400cyc) covered (depth-1 only covered ~200).
// WAR safe: STAGE(kt+2) writes buf[(kt-1)%3], readers done at kt-1 barrier.
// MODE 0 (stage 1): Q/K -> per-head [bsh][l][c]; V -> TRANSPOSED [bsh][c][l]
//   via MFMA operand swap. MODE 1: Q/K -> [blh][s][c]; V row-major.
template<int MODE>
__global__ __launch_bounds__(256) void k_gemm(
    const u16* __restrict__ A, const u16* __restrict__ W,
    const float* __restrict__ bias,
    u16* __restrict__ D0, u16* __restrict__ D1, u16* __restrict__ D2) {
  __shared__ u16 Sg[24576];  // 3 bufs @ b*8192: A[128][32] @+0, W @+4096
  const int lin = blockIdx.x;
  const int j = lin >> 3, xcd = lin & 7;
  const int bx = j % 12;
  const int by = xcd * 32 + j / 12;
  const int t = threadIdx.x;
  const int w = t >> 6, lane = t & 63, lr = lane & 15, lk = lane >> 4;
  const int wr = w >> 1, wc = w & 1;
  const bool vblk = (bx >= 8) && (MODE == 0);

  f32x4 acc[4][4];
#pragma unroll
  for (int i = 0; i < 4; i++)
#pragma unroll
    for (int jj = 0; jj < 4; jj++) acc[i][jj] = fz4();

  const int srow = w * 32 + (lane >> 2);
  const int scol = (lane & 3) * 8;
  const u16* Ap = A + (size_t)(by * 128 + srow) * 512 + scol;
  const u16* Wp = W + (size_t)(bx * 128 + srow) * 512 + scol;
  const int wb = w * 1024;  // wave-local staging base (u16)

#define STAGE(kt_, buf_)                                            \
  {                                                                 \
    const int k_ = (kt_) * 32;                                      \
    const int b_ = (buf_) * 8192;                                   \
    gl16(Ap + k_, &Sg[b_ + wb]);                                    \
    gl16(Ap + k_ + 16 * 512, &Sg[b_ + wb + 512]);                   \
    gl16(Wp + k_, &Sg[b_ + 4096 + wb]);                             \
    gl16(Wp + k_ + 16 * 512, &Sg[b_ + 4096 + wb + 512]);            \
  }

#define COMPUTE(cur_)                                                             \
  {                                                                               \
    const int c_ = (cur_) * 8192;                                                 \
    s16x8 aq[4], bq[4];                                                           \
    _Pragma("unroll")                                                             \
    for (int mi = 0; mi < 4; mi++)                                                \
      aq[mi] = *reinterpret_cast<const s16x8*>(                                   \
          &Sg[c_ + (wr * 64 + mi * 16 + lr) * 32 + lk * 8]);                      \
    _Pragma("unroll")                                                             \
    for (int ni = 0; ni < 4; ni++)                                                \
      bq[ni] = *reinterpret_cast<const s16x8*>(                                   \
          &Sg[c_ + 4096 + (wc * 64 + ni * 16 + lr) * 32 + lk * 8]);               \
    if (!vblk) {                                                                  \
      _Pragma("unroll")                                                           \
      for (int mi = 0; mi < 4; mi++)                                              \
        _Pragma("unroll")                                                         \
        for (int ni = 0; ni < 4; ni++)                                            \
          acc[mi][ni] = __builtin_amdgcn_mfma_f32_16x16x32_bf16(                  \
              aq[mi], bq[ni], acc[mi][ni], 0, 0, 0);                              \
    } else {                                                                      \
      _Pragma("unroll")                                                           \
      for (int mi = 0; mi < 4; mi++)                                              \
        _Pragma("unroll")                                                         \
        for (int ni = 0; ni < 4; ni++)                                            \
          acc[mi][ni] = __builtin_amdgcn_mfma_f32_16x16x32_bf16(                  \
              bq[ni], aq[mi], acc[mi][ni], 0, 0, 0);                              \
    }                                                                             \
  }

  // prologue: stage tiles 0,1 into bufs 0,1 (8 loads outstanding)
  STAGE(0, 0)
  STAGE(1, 1)

  // main: kt=0..13, stage kt+2, steady 12 outstanding, certify group kt
  for (int kt = 0; kt < 14; ++kt) {
    STAGE(kt + 2, (kt + 2) % 3)
    asm volatile("s_waitcnt vmcnt(8)" ::: "memory");   // own group kt landed
    asm volatile("s_barrier" ::: "memory");            // ALL groups kt landed
    COMPUTE(kt % 3)
    asm volatile("s_barrier" ::: "memory");            // WAR: buf reusable
  }
  // kt=14: groups 14,15 outstanding
  asm volatile("s_waitcnt vmcnt(4)" ::: "memory");
  asm volatile("s_barrier" ::: "memory");
  COMPUTE(2)   // 14%3
  asm volatile("s_barrier" ::: "memory");
  // kt=15
  asm volatile("s_waitcnt vmcnt(0)" ::: "memory");
  asm volatile("s_barrier" ::: "memory");
  COMPUTE(0)   // 15%3

#undef STAGE
#undef COMPUTE

  const int colg = bx * 2 + wc;  // col>>6
  if (MODE == 0) {
    const int bs = by >> 1;
    if (!vblk) {
      u16* dst = (colg < 8) ? D0 : D1;  // Qh : Kh
      const int h = colg & 7;
      const size_t hb = (size_t)(bs * 8 + h) * 16384;
#pragma unroll
      for (int ni = 0; ni < 4; ni++) {
        const int c = ni * 16 + lr;
        const float bv = bias[(colg << 6) + c];
#pragma unroll
        for (int mi = 0; mi < 4; mi++) {
          const int l0 = (by & 1) * 128 + wr * 64 + mi * 16 + lk * 4;
#pragma unroll
          for (int q = 0; q < 4; q++)
            dst[hb + (size_t)(l0 + q) * 64 + c] = f2bf(acc[mi][ni][q] + bv);
        }
      }
    } else {
      const int h = colg & 7;
      const size_t hb = (size_t)(bs * 8 + h) * 16384;
#pragma unroll
      for (int ni = 0; ni < 4; ni++) {
        const int c0 = ni * 16 + lk * 4;
        const f32x4 bv4 = *reinterpret_cast<const f32x4*>(&bias[(colg << 6) + c0]);
#pragma unroll
        for (int mi = 0; mi < 4; mi++) {
          const int l = (by & 1) * 128 + wr * 64 + mi * 16 + lr;
#pragma unroll
          for (int q = 0; q < 4; q++)
            D2[hb + (size_t)(c0 + q) * 256 + l] = f2bf(acc[mi][ni][q] + bv4[q]);
        }
      }
    }
  } else {
    if (colg < 16) {
      u16* dst = (colg < 8) ? D0 : D1;  // Qc2 : Kc2  [blh][s][c]
      const int h = colg & 7;
#pragma unroll
      for (int ni = 0; ni < 4; ni++) {
        const int c = ni * 16 + lr;
        const float bv = bias[(colg << 6) + c];
#pragma unroll
        for (int mi = 0; mi < 4; mi++) {
          const int r0 = by * 128 + wr * 64 + mi * 16 + lk * 4;
#pragma unroll
          for (int q = 0; q < 4; q++) {
            const int row = r0 + q;
            const int b = row >> 14, s = (row >> 8) & 63, l = row & 255;
            dst[(((size_t)(b * 256 + l) * 8 + h) * 64 + s) * 64 + c] = f2bf(acc[mi][ni][q] + bv);
          }
        }
      }
    } else {
      // V row-major [row][512]
#pragma unroll
      for (int ni = 0; ni < 4; ni++) {
        const int c512 = (bx - 8) * 128 + wc * 64 + ni * 16 + lr;
        const float bv = bias[1024 + c512];
#pragma unroll
        for (int mi = 0; mi < 4; mi++) {
          const int r0 = by * 128 + wr * 64 + mi * 16 + lk * 4;
#pragma unroll
          for (int q = 0; q < 4; q++)
            D2[(size_t)(r0 + q) * 512 + c512] = f2bf(acc[mi][ni][q] + bv);
        }
      }
    }
  }
}

// ---------------------------------------------------------------------------
// Row attention: block = (qt, bsh), 64 queries vs 256 keys. Wave owns 16 q
// rows x all 256 k (in-register softmax, 16-lane shfl). P overlays K buffer.
__global__ __launch_bounds__(256) void k_row_attn(
    const u16* __restrict__ Qh, const u16* __restrict__ Kh,
    const u16* __restrict__ Vth, u16* __restrict__ O) {
  __shared__ u16 KP[256 * 72];   // K stage [256][72]; later P [64][264]
  __shared__ u16 Vt[64 * 264];   // V^T stage [64][264]
  const int lin = blockIdx.x;
  const int qt = (lin >> 3) & 3;
  const int bsh = (lin & 7) + (lin >> 5) * 8;
  const int h = bsh & 7, bs = bsh >> 3;
  const int t = threadIdx.x, w = t >> 6, lane = t & 63, lr = lane & 15, lk = lane >> 4;
  const u16* kg = Kh + (size_t)bsh * 16384;
  const u16* vg = Vth + (size_t)bsh * 16384;
#pragma unroll
  for (int u = 0; u < 8; u++)
    *reinterpret_cast<s16x8*>(&KP[t * 72 + u * 8]) =
        *reinterpret_cast<const s16x8*>(&kg[t * 64 + u * 8]);
#pragma unroll
  for (int i = 0; i < 8; i++) {
    const int id = i * 256 + t;
    const int r = id >> 5, ch = id & 31;
    *reinterpret_cast<s16x8*>(&Vt[r * 264 + ch * 8]) =
        *reinterpret_cast<const s16x8*>(&vg[r * 256 + ch * 8]);
  }
  const u16* qg = Qh + (size_t)bsh * 16384 + (size_t)(qt * 64 + w * 16 + lr) * 64 + lk * 8;
  const s16x8 aq0 = *reinterpret_cast<const s16x8*>(qg);
  const s16x8 aq1 = *reinterpret_cast<const s16x8*>(qg + 32);
  __syncthreads();

  f32x4 sc[16];
#pragma unroll
  for (int ni = 0; ni < 16; ni++) sc[ni] = fz4();
#pragma unroll
  for (int ni = 0; ni < 16; ni++) {
    const s16x8 b0 = *reinterpret_cast<const s16x8*>(&KP[(ni * 16 + lr) * 72 + lk * 8]);
    sc[ni] = __builtin_amdgcn_mfma_f32_16x16x32_bf16(aq0, b0, sc[ni], 0, 0, 0);
  }
#pragma unroll
  for (int ni = 0; ni < 16; ni++) {
    const s16x8 b1 = *reinterpret_cast<const s16x8*>(&KP[(ni * 16 + lr) * 72 + 32 + lk * 8]);
    sc[ni] = __builtin_amdgcn_mfma_f32_16x16x32_bf16(aq1, b1, sc[ni], 0, 0, 0);
  }
  // softmax: rows w*16 + lk*4 + qi, reduce over 16 frags + 16 lr lanes
  float mx[4], sm[4];
#pragma unroll
  for (int qi = 0; qi < 4; qi++) {
    float m = sc[0][qi];
#pragma unroll
    for (int ni = 1; ni < 16; ni++) m = fmaxf(m, sc[ni][qi]);
    mx[qi] = m;
  }
#pragma unroll
  for (int d = 1; d < 16; d <<= 1)
#pragma unroll
    for (int qi = 0; qi < 4; qi++) mx[qi] = fmaxf(mx[qi], __shfl_xor(mx[qi], d));
#pragma unroll
  for (int qi = 0; qi < 4; qi++) sm[qi] = 0.f;
#pragma unroll
  for (int ni = 0; ni < 16; ni++)
#pragma unroll
    for (int qi = 0; qi < 4; qi++) {
      const float p = __expf(sc[ni][qi] - mx[qi]);
      sc[ni][qi] = p;
      sm[qi] += p;
    }
#pragma unroll
  for (int d = 1; d < 16; d <<= 1)
#pragma unroll
    for (int qi = 0; qi < 4; qi++) sm[qi] += __shfl_xor(sm[qi], d);
  float inv[4];
#pragma unroll
  for (int qi = 0; qi < 4; qi++) inv[qi] = 1.f / sm[qi];
  __syncthreads();  // all waves done reading K
#pragma unroll
  for (int ni = 0; ni < 16; ni++)
#pragma unroll
    for (int qi = 0; qi < 4; qi++)
      KP[(w * 16 + lk * 4 + qi) * 264 + ni * 16 + lr] = f2bf(sc[ni][qi] * inv[qi]);
  __syncthreads();

  f32x4 o[4];
#pragma unroll
  for (int mi = 0; mi < 4; mi++) o[mi] = fz4();
#pragma unroll
  for (int ks = 0; ks < 8; ks++) {
    const s16x8 vb = *reinterpret_cast<const s16x8*>(&Vt[(w * 16 + lr) * 264 + ks * 32 + lk * 8]);
#pragma unroll
    for (int mi = 0; mi < 4; mi++) {
      const s16x8 pa = *reinterpret_cast<const s16x8*>(&KP[(mi * 16 + lr) * 264 + ks * 32 + lk * 8]);
      o[mi] = __builtin_amdgcn_mfma_f32_16x16x32_bf16(pa, vb, o[mi], 0, 0, 0);
    }
  }
  const size_t ob = (size_t)bs * 131072 + (size_t)qt * 64 * 512 + h * 64 + w * 16 + lr;
#pragma unroll
  for (int mi = 0; mi < 4; mi++)
#pragma unroll
    for (int qi = 0; qi < 4; qi++)
      O[ob + (size_t)(mi * 16 + lk * 4 + qi) * 512] = f2bf(o[mi][qi]);
}

// ---------------------------------------------------------------------------
// Column attention: per (b,l,h): QK^T (64x64,K=64) -> softmax over j -> PV.
__global__ __launch_bounds__(256) void k_col(
    const u16* __restrict__ Qc, const u16* __restrict__ Kc,
    const u16* __restrict__ V2, u16* __restrict__ O) {
  __shared__ u16 Qs[64][72];
  __shared__ u16 Ks[64][72];
  __shared__ u16 Pl[64][72];
  __shared__ u16 Vt[64][72];
  __shared__ float red[2][64][2];
  const int bid = blockIdx.x;
  const int h = bid & 7, bl = bid >> 3;
  const int l_ = bl & 255, b = bl >> 8;
  const size_t base = ((size_t)(b * 256 + l_) * 8 + h) * 4096;
  const int t = threadIdx.x;
  const int r = t >> 2, c0 = (t & 3) * 16;
  *reinterpret_cast<s16x8*>(&Qs[r][c0]) = *reinterpret_cast<const s16x8*>(&Qc[base + r * 64 + c0]);
  *reinterpret_cast<s16x8*>(&Qs[r][c0 + 8]) = *reinterpret_cast<const s16x8*>(&Qc[base + r * 64 + c0 + 8]);
  *reinterpret_cast<s16x8*>(&Ks[r][c0]) = *reinterpret_cast<const s16x8*>(&Kc[base + r * 64 + c0]);
  *reinterpret_cast<s16x8*>(&Ks[r][c0 + 8]) = *reinterpret_cast<const s16x8*>(&Kc[base + r * 64 + c0 + 8]);
  __syncthreads();
  const int w = t >> 6, l = t & 63, lr = l & 15, lk = l >> 4;
  const int wr = w >> 1, wc = w & 1;
  f32x4 acc[2][2];
#pragma unroll
  for (int i = 0; i < 2; i++)
#pragma unroll
    for (int jj = 0; jj < 2; jj++) acc[i][jj] = fz4();
#pragma unroll
  for (int ks = 0; ks < 2; ks++) {
    s16x8 aq[2], bq[2];
#pragma unroll
    for (int mi = 0; mi < 2; mi++)
      aq[mi] = *reinterpret_cast<const s16x8*>(&Qs[wr * 32 + mi * 16 + lr][ks * 32 + lk * 8]);
#pragma unroll
    for (int ni = 0; ni < 2; ni++)
      bq[ni] = *reinterpret_cast<const s16x8*>(&Ks[wc * 32 + ni * 16 + lr][ks * 32 + lk * 8]);
#pragma unroll
    for (int mi = 0; mi < 2; mi++)
#pragma unroll
      for (int ni = 0; ni < 2; ni++)
        acc[mi][ni] = __builtin_amdgcn_mfma_f32_16x16x32_bf16(aq[mi], bq[ni], acc[mi][ni], 0, 0, 0);
  }
  float mloc[2][4];
#pragma unroll
  for (int mi = 0; mi < 2; mi++)
#pragma unroll
    for (int q = 0; q < 4; q++) mloc[mi][q] = fmaxf(acc[mi][0][q], acc[mi][1][q]);
#pragma unroll
  for (int d = 1; d < 16; d <<= 1)
#pragma unroll
    for (int mi = 0; mi < 2; mi++)
#pragma unroll
      for (int q = 0; q < 4; q++)
        mloc[mi][q] = fmaxf(mloc[mi][q], __shfl_xor(mloc[mi][q], d));
  if (lr == 0)
#pragma unroll
    for (int mi = 0; mi < 2; mi++)
#pragma unroll
      for (int q = 0; q < 4; q++) red[0][wr * 32 + mi * 16 + lk * 4 + q][wc] = mloc[mi][q];
  __syncthreads();
  float mg[2][4], ss[2][4];
#pragma unroll
  for (int mi = 0; mi < 2; mi++)
#pragma unroll
    for (int q = 0; q < 4; q++) {
      const int r0 = wr * 32 + mi * 16 + lk * 4 + q;
      mg[mi][q] = fmaxf(red[0][r0][0], red[0][r0][1]);
      ss[mi][q] = 0.f;
    }
#pragma unroll
  for (int mi = 0; mi < 2; mi++)
#pragma unroll
    for (int ni = 0; ni < 2; ni++)
#pragma unroll
      for (int q = 0; q < 4; q++) {
        const float p = __expf(acc[mi][ni][q] - mg[mi][q]);
        acc[mi][ni][q] = p;
        ss[mi][q] += p;
      }
#pragma unroll
  for (int d = 1; d < 16; d <<= 1)
#pragma unroll
    for (int mi = 0; mi < 2; mi++)
#pragma unroll
      for (int q = 0; q < 4; q++) ss[mi][q] += __shfl_xor(ss[mi][q], d);
  if (lr == 0)
#pragma unroll
    for (int mi = 0; mi < 2; mi++)
#pragma unroll
      for (int q = 0; q < 4; q++) red[1][wr * 32 + mi * 16 + lk * 4 + q][wc] = ss[mi][q];
  __syncthreads();
#pragma unroll
  for (int mi = 0; mi < 2; mi++)
#pragma unroll
    for (int q = 0; q < 4; q++) {
      const int r0 = wr * 32 + mi * 16 + lk * 4 + q;
      const float inv = 1.f / (red[1][r0][0] + red[1][r0][1]);
#pragma unroll
      for (int ni = 0; ni < 2; ni++)
        Pl[r0][wc * 32 + ni * 16 + lr] = f2bf(acc[mi][ni][q] * inv);
    }
  __syncthreads();
  {
    const u16* vg = V2 + ((size_t)(b * 64) * 256 + l_) * 512 + h * 64;
#pragma unroll
    for (int u = 0; u < 4; u++) {
      U16x4 vv = *reinterpret_cast<const U16x4*>(&vg[(size_t)r * 131072 + c0 + u * 4]);
      Vt[c0 + u * 4 + 0][r] = vv.a; Vt[c0 + u * 4 + 1][r] = vv.b;
      Vt[c0 + u * 4 + 2][r] = vv.c; Vt[c0 + u * 4 + 3][r] = vv.d;
    }
  }
  __syncthreads();
  f32x4 acc2[2][2];
#pragma unroll
  for (int i = 0; i < 2; i++)
#pragma unroll
    for (int jj = 0; jj < 2; jj++) acc2[i][jj] = fz4();
#pragma unroll
  for (int ks = 0; ks < 2; ks++) {
    s16x8 ap[2], bp[2];
#pragma unroll
    for (int mi = 0; mi < 2; mi++)
      ap[mi] = *reinterpret_cast<const s16x8*>(&Pl[wr * 32 + mi * 16 + lr][ks * 32 + lk * 8]);
#pragma unroll
    for (int ni = 0; ni < 2; ni++)
      bp[ni] = *reinterpret_cast<const s16x8*>(&Vt[wc * 32 + ni * 16 + lr][ks * 32 + lk * 8]);
#pragma unroll
    for (int mi = 0; mi < 2; mi++)
#pragma unroll
      for (int ni = 0; ni < 2; ni++)
        acc2[mi][ni] = __builtin_amdgcn_mfma_f32_16x16x32_bf16(ap[mi], bp[ni], acc2[mi][ni], 0, 0, 0);
  }
  const size_t ob = ((size_t)b * 16384 + l_) * 512 + h * 64;
#pragma unroll
  for (int mi = 0; mi < 2; mi++)
#pragma unroll
    for (int ni = 0; ni < 2; ni++)
#pragma unroll
      for (int q = 0; q < 4; q++) {
        const int i = wr * 32 + mi * 16 + lk * 4 + q;
        const int cc = wc * 32 + ni * 16 + lr;
        O[ob + (size_t)i * 131072 + cc] = f2bf(acc2[mi][ni][q]);
      }
}

// ---------------------------------------------------------------------------
// LN1: base bf16 (abf = x rounded) + add bf16 -> out bf16.
__global__ __launch_bounds__(256) void k_ln1(
    const u16* __restrict__ xin, const u16* __restrict__ add,
    const float* __restrict__ g, const float* __restrict__ be,
    u16* __restrict__ outp) {
  const int w = threadIdx.x >> 6, l = threadIdx.x & 63;
  const size_t row = (size_t)blockIdx.x * 4 + w;
  const size_t o = row * 512 + l * 8;
  U16x4 x0 = *reinterpret_cast<const U16x4*>(xin + o);
  U16x4 x1 = *reinterpret_cast<const U16x4*>(xin + o + 4);
  U16x4 a0 = *reinterpret_cast<const U16x4*>(add + o);
  U16x4 a1 = *reinterpret_cast<const U16x4*>(add + o + 4);
  float v[8] = {bf2f(x0.a) + bf2f(a0.a), bf2f(x0.b) + bf2f(a0.b),
                bf2f(x0.c) + bf2f(a0.c), bf2f(x0.d) + bf2f(a0.d),
                bf2f(x1.a) + bf2f(a1.a), bf2f(x1.b) + bf2f(a1.b),
                bf2f(x1.c) + bf2f(a1.c), bf2f(x1.d) + bf2f(a1.d)};
  float s = 0.f, sq = 0.f;
#pragma unroll
  for (int i = 0; i < 8; i++) { s += v[i]; sq += v[i] * v[i]; }
#pragma unroll
  for (int d = 1; d < 64; d <<= 1) { s += __shfl_xor(s, d); sq += __shfl_xor(sq, d); }
  const float mu = s * (1.f / 512.f);
  const float var = sq * (1.f / 512.f) - mu * mu;
  const float rstd = rsqrtf(fmaxf(var, 0.f) + 1e-5f);
  U16x4 r0, r1;
  const float* gp = g + l * 8;
  const float* bp = be + l * 8;
  r0.a = f2bf((v[0] - mu) * rstd * gp[0] + bp[0]);
  r0.b = f2bf((v[1] - mu) * rstd * gp[1] + bp[1]);
  r0.c = f2bf((v[2] - mu) * rstd * gp[2] + bp[2]);
  r0.d = f2bf((v[3] - mu) * rstd * gp[3] + bp[3]);
  r1.a = f2bf((v[4] - mu) * rstd * gp[4] + bp[4]);
  r1.b = f2bf((v[5] - mu) * rstd * gp[5] + bp[5]);
  r1.c = f2bf((v[6] - mu) * rstd * gp[6] + bp[6]);
  r1.d = f2bf((v[7] - mu) * rstd * gp[7] + bp[7]);
  *reinterpret_cast<U16x4*>(outp + o) = r0;
  *reinterpret_cast<U16x4*>(outp + o + 4) = r1;
}

__global__ __launch_bounds__(256) void k_ln2(
    const u16* __restrict__ xin, const u16* __restrict__ add,
    const float* __restrict__ g, const float* __restrict__ be,
    float* __restrict__ outp) {
  const int w = threadIdx.x >> 6, l = threadIdx.x & 63;
  const size_t row = (size_t)blockIdx.x * 4 + w;
  const size_t o = row * 512 + l * 8;
  U16x4 x0 = *reinterpret_cast<const U16x4*>(xin + o);
  U16x4 x1 = *reinterpret_cast<const U16x4*>(xin + o + 4);
  U16x4 a0 = *reinterpret_cast<const U16x4*>(add + o);
  U16x4 a1 = *reinterpret_cast<const U16x4*>(add + o + 4);
  float v[8] = {bf2f(x0.a) + bf2f(a0.a), bf2f(x0.b) + bf2f(a0.b),
                bf2f(x0.c) + bf2f(a0.c), bf2f(x0.d) + bf2f(a0.d),
                bf2f(x1.a) + bf2f(a1.a), bf2f(x1.b) + bf2f(a1.b),
                bf2f(x1.c) + bf2f(a1.c), bf2f(x1.d) + bf2f(a1.d)};
  float s = 0.f, sq = 0.f;
#pragma unroll
  for (int i = 0; i < 8; i++) { s += v[i]; sq += v[i] * v[i]; }
#pragma unroll
  for (int d = 1; d < 64; d <<= 1) { s += __shfl_xor(s, d); sq += __shfl_xor(sq, d); }
  const float mu = s * (1.f / 512.f);
  const float var = sq * (1.f / 512.f) - mu * mu;
  const float rstd = rsqrtf(fmaxf(var, 0.f) + 1e-5f);
  f32x4 g0 = *reinterpret_cast<const f32x4*>(g + l * 8);
  f32x4 g1v = *reinterpret_cast<const f32x4*>(g + l * 8 + 4);
  f32x4 b0 = *reinterpret_cast<const f32x4*>(be + l * 8);
  f32x4 b1 = *reinterpret_cast<const f32x4*>(be + l * 8 + 4);
  f32x4 o0, o1;
  o0.x = (v[0] - mu) * rstd * g0.x + b0.x;
  o0.y = (v[1] - mu) * rstd * g0.y + b0.y;
  o0.z = (v[2] - mu) * rstd * g0.z + b0.z;
  o0.w = (v[3] - mu) * rstd * g0.w + b0.w;
  o1.x = (v[4] - mu) * rstd * g1v.x + b1.x;
  o1.y = (v[5] - mu) * rstd * g1v.y + b1.y;
  o1.z = (v[6] - mu) * rstd * g1v.z + b1.z;
  o1.w = (v[7] - mu) * rstd * g1v.w + b1.w;
  *reinterpret_cast<f32x4*>(outp + o) = o0;
  *reinterpret_cast<f32x4*>(outp + o + 4) = o1;
}

// ---------------------------------------------------------------------------
extern "C" void kernel_launch(void* const* d_in, const int* in_sizes, int n_in,
                              void* d_out, int out_size, void* d_ws, size_t ws_size,
                              hipStream_t stream) {
  const float* x     = (const float*)d_in[0];
  const float* w_row = (const float*)d_in[1];
  const float* b_row = (const float*)d_in[2];
  const float* w_col = (const float*)d_in[3];
  const float* b_col = (const float*)d_in[4];
  const float* g1    = (const float*)d_in[5];
  const float* be1   = (const float*)d_in[6];
  const float* g2    = (const float*)d_in[7];
  const float* be2   = (const float*)d_in[8];
  float* out = (float*)d_out;
  char* ws = (char*)d_ws;

  // workspace (bytes), total 202,899,456
  u16* abf   = (u16*)(ws);                  // 33.5 MB  x bf16 / stage2: Qc2
  u16* Qh    = (u16*)(ws + 33554432);       // 33.5 MB  Qh / stage2: Kc2
  u16* Kh    = (u16*)(ws + 67108864);       // 33.5 MB  Kh / stage2: V2
  u16* Vth   = (u16*)(ws + 100663296);      // 33.5 MB  V^T per-head
  u16* attnb = (u16*)(ws + 134217728);      // 33.5 MB  attention out bf16
  u16* out1b = (u16*)(ws + 167772160);      // 33.5 MB  LN1 out bf16
  u16* wbf   = (u16*)(ws + 201326592);      //  1.5 MB  W bf16
  const size_t NEED = 202899456;
  if (ws_size < NEED) {
    hipMemsetAsync(d_out, 0, (size_t)out_size * 4, stream);
    return;
  }
  u16* Qc2 = abf;
  u16* Kc2 = Qh;
  u16* V2  = Kh;

  // ---- stage 1: row attention ----
  k_cvt<<<16384, 256, 0, stream>>>(x, abf, 4194304);
  k_cvt<<<768, 256, 0, stream>>>(w_row, wbf, 196608);
  k_gemm<0><<<3072, 256, 0, stream>>>(abf, wbf, b_row, Qh, Kh, Vth);
  k_row_attn<<<4096, 256, 0, stream>>>(Qh, Kh, Vth, attnb);
  k_ln1<<<8192, 256, 0, stream>>>(abf, attnb, g1, be1, out1b);

  // ---- stage 2: column attention ----
  k_cvt<<<768, 256, 0, stream>>>(w_col, wbf, 196608);
  k_gemm<1><<<3072, 256, 0, stream>>>(out1b, wbf, b_col, Qc2, Kc2, V2);
  k_col<<<4096, 256, 0, stream>>>(Qc2, Kc2, V2, attnb);
  k_ln2<<<8192, 256, 0, stream>>>(out1b, attnb, g2, be2, out);
}